// Round 12
// baseline (130.314 us; speedup 1.0000x reference)
//
#include <hip/hip_runtime.h>
#include <hip/hip_bf16.h>
#include <stdint.h>

typedef __attribute__((ext_vector_type(8))) __bf16 bf16x8;
typedef __attribute__((ext_vector_type(4))) float f32x4;
typedef __attribute__((ext_vector_type(16))) float f32x16;
typedef __attribute__((ext_vector_type(2))) uint32_t u32x2;

#define MFMA16(a, b, c) __builtin_amdgcn_mfma_f32_16x16x32_bf16(a, b, c, 0, 0, 0)
#define MFMA32(a, b, c) __builtin_amdgcn_mfma_f32_32x32x16_bf16(a, b, c, 0, 0, 0)

typedef const __attribute__((address_space(1))) uint32_t* gas_ptr;
typedef __attribute__((address_space(3))) uint32_t* lds_ptr;

static __device__ __forceinline__ ushort f2b(float f) {
  union { float f; uint32_t u; } x; x.f = f;
  uint32_t u = x.u + 0x7fffu + ((x.u >> 16) & 1u);
  return (ushort)(u >> 16);
}

static __device__ __forceinline__ void g2lds16(const void* g, void* l) {
  __builtin_amdgcn_global_load_lds((gas_ptr)(uintptr_t)g, (lds_ptr)(uintptr_t)l, 16, 0, 0);
}

// counted vmcnt (T4): leave prefetch in flight across the barrier
template <int N> static __device__ __forceinline__ void waitvm() {
  if constexpr (N == 0) asm volatile("s_waitcnt vmcnt(0)" ::: "memory");
  else if constexpr (N == 4) asm volatile("s_waitcnt vmcnt(4)" ::: "memory");
  else if constexpr (N == 6) asm volatile("s_waitcnt vmcnt(6)" ::: "memory");
  else if constexpr (N == 8) asm volatile("s_waitcnt vmcnt(8)" ::: "memory");
}

static __device__ __forceinline__ u32x2 plswap(uint32_t a, uint32_t b) {
  return __builtin_amdgcn_permlane32_swap(a, b, false, false);
}
static __device__ __forceinline__ float xhalf_max(float x) {
  u32x2 r = plswap(__float_as_uint(x), __float_as_uint(x));
  return fmaxf(__uint_as_float(r.x), __uint_as_float(r.y));
}
static __device__ __forceinline__ float xhalf_sum(float x) {
  u32x2 r = plswap(__float_as_uint(x), __float_as_uint(x));
  return __uint_as_float(r.x) + __uint_as_float(r.y);
}

// ---------------- prep: cvt x -> bf16, transpose Wqkv & Wout -> bf16 [N][K] ----------------
__global__ __launch_bounds__(256) void prep(const float* __restrict__ x, ushort* __restrict__ xb,
                                            const float* __restrict__ Wqkv, ushort* __restrict__ w1t,
                                            const float* __restrict__ Wout, ushort* __restrict__ w2t,
                                            int L) {
  const int b = blockIdx.x, t = threadIdx.x;
  const int ncvt = (L * 1024) / (256 * 4);  // 2048
  if (b < ncvt) {
    int i = (b * 256 + t) * 4;
    float4 v = *(const float4*)(x + i);
    ushort4 o;
    o.x = f2b(v.x); o.y = f2b(v.y); o.z = f2b(v.z); o.w = f2b(v.w);
    *(ushort4*)(xb + i) = o;
    return;
  }
  __shared__ ushort tile[64][65];
  const float* in; ushort* out; int N; int b2;
  const int K = 1024;
  if (b < ncvt + 768) { b2 = b - ncvt; N = 3072; in = Wqkv; out = w1t; }
  else                { b2 = b - ncvt - 768; N = 1024; in = Wout; out = w2t; }
  int nx = b2 % (N >> 6), ky = b2 / (N >> 6);
  int n0 = nx * 64, k0 = ky * 64;
#pragma unroll
  for (int i = 0; i < 16; ++i) {
    int idx = i * 256 + t;
    int r = idx >> 6, c = idx & 63;
    tile[r][c] = f2b(in[(size_t)(k0 + r) * N + n0 + c]);
  }
  __syncthreads();
#pragma unroll
  for (int i = 0; i < 16; ++i) {
    int idx = i * 256 + t;
    int r = idx >> 6, c = idx & 63;  // r = n index, c = k index
    out[(size_t)(n0 + r) * K + k0 + c] = tile[c][r];
  }
}

// ---------------- dbuf bf16 GEMM with counted vmcnt: C = A*Bt^T (+bias), fp32 C ----------------
template <int BM, int BN, bool BIAS>
__global__ __launch_bounds__(256) void gemm_dbuf(const ushort* __restrict__ A,
                                                 const ushort* __restrict__ Bt,
                                                 float* __restrict__ C,
                                                 const float* __restrict__ bias,
                                                 int M, int N, int K) {
  constexpr int WM = BM / 2, WN = BN / 2, MF = WM / 16, NF = WN / 16;
  constexpr int AI = BM / 32, BI = BN / 32;
  __shared__ ushort lA[2][BM * 64];
  __shared__ ushort lB[2][BN * 64];
  const int t = threadIdx.x, lane = t & 63;
  const int bm = blockIdx.y * BM, bn = blockIdx.x * BN;
  const int wid = t >> 6, wr = wid >> 1, wc = wid & 1;

  f32x4 acc[MF][NF] = {};

  auto STAGE = [&](int bb, int k0) {
#pragma unroll
    for (int i = 0; i < AI; ++i) {
      int ci = i * 256 + t;
      int r = ci >> 3, cs = ci & 7;
      int cg = (cs ^ (r & 7)) * 8;
      g2lds16(A + (size_t)(bm + r) * K + k0 + cg, (ushort*)lA[bb] + ci * 8);
    }
#pragma unroll
    for (int i = 0; i < BI; ++i) {
      int ci = i * 256 + t;
      int r = ci >> 3, cs = ci & 7;
      int cg = (cs ^ (r & 7)) * 8;
      g2lds16(Bt + (size_t)(bn + r) * K + k0 + cg, (ushort*)lB[bb] + ci * 8);
    }
  };

  STAGE(0, 0);
  const int NS = K >> 6;
  int buf = 0;
  for (int s = 0; s < NS; ++s) {
    if (s + 1 < NS) { STAGE(buf ^ 1, (s + 1) << 6); waitvm<AI + BI>(); }
    else            { waitvm<0>(); }
    __builtin_amdgcn_s_barrier();
    __builtin_amdgcn_sched_barrier(0);
#pragma unroll
    for (int kk = 0; kk < 2; ++kk) {
      bf16x8 af[MF], bfr[NF];
#pragma unroll
      for (int m = 0; m < MF; ++m) {
        int row = wr * WM + m * 16 + (lane & 15);
        int cb = kk * 64 + ((lane >> 4) << 4);
        int sw = cb ^ ((row & 7) << 4);
        af[m] = *(const bf16x8*)((const char*)lA[buf] + row * 128 + sw);
      }
#pragma unroll
      for (int n = 0; n < NF; ++n) {
        int row = wc * WN + n * 16 + (lane & 15);
        int cb = kk * 64 + ((lane >> 4) << 4);
        int sw = cb ^ ((row & 7) << 4);
        bfr[n] = *(const bf16x8*)((const char*)lB[buf] + row * 128 + sw);
      }
      __builtin_amdgcn_s_setprio(1);
#pragma unroll
      for (int m = 0; m < MF; ++m)
#pragma unroll
        for (int n = 0; n < NF; ++n) acc[m][n] = MFMA16(af[m], bfr[n], acc[m][n]);
      __builtin_amdgcn_s_setprio(0);
    }
    __builtin_amdgcn_s_barrier();      // readers done before next STAGE overwrites
    __builtin_amdgcn_sched_barrier(0);
    buf ^= 1;
  }
#pragma unroll
  for (int m = 0; m < MF; ++m) {
#pragma unroll
    for (int n = 0; n < NF; ++n) {
      int col = bn + wc * WN + n * 16 + (lane & 15);
      float b = BIAS ? bias[col] : 0.f;
#pragma unroll
      for (int r = 0; r < 4; ++r) {
        int row = bm + wr * WM + m * 16 + ((lane >> 4) << 2) + r;
        C[(size_t)row * N + col] = acc[m][n][r] + b;
      }
    }
  }
}

// ---------------- fused qkv GEMM (dbuf, counted vmcnt) ----------------
__global__ __launch_bounds__(256) void gemm_qkv(const ushort* __restrict__ A,
                                                const ushort* __restrict__ Bt,
                                                const float* __restrict__ bqkv,
                                                const float* __restrict__ rel,
                                                ushort* __restrict__ Qs,
                                                ushort* __restrict__ Kp,
                                                ushort* __restrict__ Vt, int M) {
  __shared__ ushort lA[2][128 * 64];
  __shared__ ushort lB[2][128 * 64];
  const int K = 1024;
  const int t = threadIdx.x, lane = t & 63;
  const int bm = blockIdx.y * 128, bn = blockIdx.x * 128;
  const int wid = t >> 6, wr = wid >> 1, wc = wid & 1;

  f32x4 acc[4][4] = {};

  auto STAGE = [&](int bb, int k0) {
#pragma unroll
    for (int i = 0; i < 4; ++i) {
      int ci = i * 256 + t;
      int r = ci >> 3, cs = ci & 7;
      int cg = (cs ^ (r & 7)) * 8;
      g2lds16(A + (size_t)(bm + r) * K + k0 + cg, (ushort*)lA[bb] + ci * 8);
      g2lds16(Bt + (size_t)(bn + r) * K + k0 + cg, (ushort*)lB[bb] + ci * 8);
    }
  };

  STAGE(0, 0);
  int buf = 0;
  for (int s = 0; s < 16; ++s) {
    if (s + 1 < 16) { STAGE(buf ^ 1, (s + 1) << 6); waitvm<8>(); }
    else            { waitvm<0>(); }
    __builtin_amdgcn_s_barrier();
    __builtin_amdgcn_sched_barrier(0);
#pragma unroll
    for (int kk = 0; kk < 2; ++kk) {
      bf16x8 af[4], bfr[4];
#pragma unroll
      for (int m = 0; m < 4; ++m) {
        int row = wr * 64 + m * 16 + (lane & 15);
        int cb = kk * 64 + ((lane >> 4) << 4);
        int sw = cb ^ ((row & 7) << 4);
        af[m] = *(const bf16x8*)((const char*)lA[buf] + row * 128 + sw);
      }
#pragma unroll
      for (int n = 0; n < 4; ++n) {
        int row = wc * 64 + n * 16 + (lane & 15);
        int cb = kk * 64 + ((lane >> 4) << 4);
        int sw = cb ^ ((row & 7) << 4);
        bfr[n] = *(const bf16x8*)((const char*)lB[buf] + row * 128 + sw);
      }
      __builtin_amdgcn_s_setprio(1);
#pragma unroll
      for (int m = 0; m < 4; ++m)
#pragma unroll
        for (int n = 0; n < 4; ++n) acc[m][n] = MFMA16(af[m], bfr[n], acc[m][n]);
      __builtin_amdgcn_s_setprio(0);
    }
    __builtin_amdgcn_s_barrier();
    __builtin_amdgcn_sched_barrier(0);
    buf ^= 1;
  }

  const int sec = bn >> 10;          // 0=Q, 1=K, 2=V
  const int cis_base = bn & 1023;
  if (sec < 2) {
    ushort* dst = (sec == 0) ? Qs : Kp;
    const float scale = (sec == 0) ? 0.18033688f : 1.0f;  // 0.125*log2(e) for Q
#pragma unroll
    for (int m = 0; m < 4; ++m) {
#pragma unroll
      for (int n = 0; n < 4; ++n) {
        int cis = cis_base + wc * 64 + n * 16 + (lane & 15);
        int hh = cis >> 6, dd = cis & 63;
        float b = bqkv[sec * 1024 + cis];
#pragma unroll
        for (int r = 0; r < 4; ++r) {
          int row = bm + wr * 64 + m * 16 + ((lane >> 4) << 2) + r;
          float v = acc[m][n][r] + b;
          if (sec == 1 && row > 0) v += rel[(size_t)(row - 1) * 64 + dd];
          dst[((size_t)hh * M + row) * 64 + dd] = f2b(v * scale);
        }
      }
    }
  } else {
    // V: bf16 into swizzled LDS [c][l], then coalesced transposed store.
    char* tb = (char*)lA;
#pragma unroll
    for (int m = 0; m < 4; ++m) {
#pragma unroll
      for (int n = 0; n < 4; ++n) {
        int cl = wc * 64 + n * 16 + (lane & 15);
        int ll = wr * 64 + m * 16 + ((lane >> 4) << 2);
        float b = bqkv[2048 + cis_base + cl];
        ushort4 w4;
        w4.x = f2b(acc[m][n][0] + b);
        w4.y = f2b(acc[m][n][1] + b);
        w4.z = f2b(acc[m][n][2] + b);
        w4.w = f2b(acc[m][n][3] + b);
        *(ushort4*)(tb + cl * 256 + ((ll * 2) ^ ((cl & 15) << 4))) = w4;
      }
    }
    __syncthreads();
#pragma unroll
    for (int ps = 0; ps < 8; ++ps) {
      int cl = ps * 16 + (t >> 4);
      int chunk = t & 15;
      uint4 rv = *(const uint4*)(tb + cl * 256 + ((chunk * 16) ^ ((cl & 15) << 4)));
      *(uint4*)(Vt + (size_t)(cis_base + cl) * M + bm + chunk * 8) = rv;
    }
  }
}

// ---------------- flash attention v11: 8 waves, 2 qt x 4 streams, reg-staged 64KB, 2 blocks/CU ----------------
// r10/r11 lesson: static LDS >= 128KB fails to launch (silent); 68KB-class works.
// This shape: 512 blocks x 512 thr; LDS ~70KB -> 2 blocks/CU -> 16 waves/CU = 4 waves/SIMD
// (the occupancy target that hides the ~600cy serial softmax chain). Single 64KB staging
// buffer (4 streams x 16KB); pipeline via T14 reg-staging: issue next tile's 8x16B global
// loads at loop top, compute current tile from LDS, barrier, ds_write regs (swizzled dest,
// same LDS image as the g2lds16 prologue), barrier. Inner loop identical to proven attn8.
__global__ __launch_bounds__(512, 4) void attn11(const ushort* __restrict__ Qs,
                                                 const ushort* __restrict__ Kp,
                                                 const ushort* __restrict__ Vt,
                                                 ushort* __restrict__ O, int L) {
  __shared__ char smem[69632];        // staging 64KB; merge (50.7KB part + 17.4KB merged) aliased
  __shared__ float mls[2][4][2][32];  // [qt][ks][m/l][q]
  const int bid = blockIdx.x;
  const int h = (bid & 7) * 2 + (bid >> 8);      // XCD (bid%8) serves heads {2c,2c+1}
  const int q0 = ((bid >> 3) & 31) * 64;
  const int t = threadIdx.x, lane = t & 63, w = t >> 6;
  const int qt = w & 1, ks = w >> 1;
  const int ql = lane & 31, hi = lane >> 5;
  const int sw = (ql & 7) << 4;
  const ushort* kh = Kp + (size_t)h * L * 64;
  const ushort* vh = Vt + (size_t)h * 64 * L;
  const int span = L >> 2;            // 512 keys per stream
  const int NT = span >> 6;           // 8 tiles per stream

  bf16x8 qf[4];
  {
    const ushort* qrow = Qs + ((size_t)h * L + q0 + qt * 32 + ql) * 64 + hi * 8;
#pragma unroll
    for (int c = 0; c < 4; ++c) qf[c] = *(const bf16x8*)(qrow + c * 16);
  }

  f32x16 ot0 = {}, ot1 = {};
  float m = -1e30f, l = 0.f;

  const int key8 = t >> 3, pch = t & 7;          // staging coords (512 units per K/V half)

  // ---- prologue: stage tile 0 of all 4 streams via g2lds16 (pre-swizzled source) ----
#pragma unroll
  for (int i = 0; i < 8; ++i) {
    int s = i >> 1;
    char* sb = smem + s * 16384;
    if ((i & 1) == 0)
      g2lds16(kh + (((size_t)(s * span + key8)) << 6) + ((pch ^ (key8 & 7)) << 3),
              sb + t * 16);
    else
      g2lds16(vh + (size_t)key8 * L + s * span + ((pch ^ (key8 & 7)) << 3),
              sb + 8192 + t * 16);
  }
  waitvm<0>();
  __builtin_amdgcn_s_barrier();
  __builtin_amdgcn_sched_barrier(0);

  const int wchunk = (pch << 4) ^ ((key8 & 7) << 4);  // swizzled dest byte offset within row

  for (int tt = 0; tt < NT; ++tt) {
    // ---- T14: issue next tile's loads into registers (linear addresses) ----
    uint4 ld[8];
    const bool pf = (tt + 1 < NT);
    if (pf) {
#pragma unroll
      for (int i = 0; i < 8; ++i) {
        int s = i >> 1;
        int kb = s * span + (tt + 1) * 64;
        if ((i & 1) == 0)
          ld[i] = *(const uint4*)(kh + (((size_t)(kb + key8)) << 6) + pch * 8);
        else
          ld[i] = *(const uint4*)(vh + (size_t)key8 * L + kb + pch * 8);
      }
    }
    // ---- compute tile tt from LDS (identical to attn8) ----
    const char* kbuf = smem + ks * 16384;
    const char* vbuf = kbuf + 8192;
    f32x16 s0 = {}, s1 = {};
    __builtin_amdgcn_s_setprio(1);
#pragma unroll
    for (int c = 0; c < 4; ++c) {
      bf16x8 k0 = *(const bf16x8*)(kbuf + ql * 128 + (((2 * c + hi) << 4) ^ sw));
      bf16x8 k1 = *(const bf16x8*)(kbuf + (32 + ql) * 128 + (((2 * c + hi) << 4) ^ sw));
      s0 = MFMA32(k0, qf[c], s0);
      s1 = MFMA32(k1, qf[c], s1);
    }
    __builtin_amdgcn_s_setprio(0);
    float mx = fmaxf(s0[0], s1[0]);
#pragma unroll
    for (int i = 1; i < 16; ++i) mx = fmaxf(fmaxf(s0[i], s1[i]), mx);
    mx = xhalf_max(mx);
    if (!__all(mx - m <= 8.0f)) {  // defer-max
      float mn = fmaxf(m, mx);
      float sc = __builtin_amdgcn_exp2f(m - mn);
      m = mn;
      l *= sc;
      ot0 = ot0 * sc;
      ot1 = ot1 * sc;
    }
    float rs = 0.f;
#pragma unroll
    for (int tl = 0; tl < 2; ++tl) {
      f32x16 s = tl ? s1 : s0;
      float p[16];
      float r0 = 0.f, r1 = 0.f;
#pragma unroll
      for (int i = 0; i < 16; i += 2) {
        p[i] = __builtin_amdgcn_exp2f(s[i] - m);
        p[i + 1] = __builtin_amdgcn_exp2f(s[i + 1] - m);
        r0 += p[i];
        r1 += p[i + 1];
      }
      rs += r0 + r1;
      uint32_t a[8];
#pragma unroll
      for (int i = 0; i < 8; ++i) {
        uint32_t r;
        asm("v_cvt_pk_bf16_f32 %0, %1, %2" : "=v"(r) : "v"(p[2 * i]), "v"(p[2 * i + 1]));
        a[i] = r;
      }
      u32x2 s02 = plswap(a[0], a[2]);
      u32x2 s13 = plswap(a[1], a[3]);
      u32x2 s46 = plswap(a[4], a[6]);
      u32x2 s57 = plswap(a[5], a[7]);
      union { uint32_t u[4]; bf16x8 v; } b0, b1;
      b0.u[0] = s02.x; b0.u[1] = s13.x; b0.u[2] = s02.y; b0.u[3] = s13.y;
      b1.u[0] = s46.x; b1.u[1] = s57.x; b1.u[2] = s46.y; b1.u[3] = s57.y;
      bf16x8 v00 = *(const bf16x8*)(vbuf + ql * 128 + (((tl * 4 + hi) << 4) ^ sw));
      bf16x8 v01 = *(const bf16x8*)(vbuf + ql * 128 + (((tl * 4 + 2 + hi) << 4) ^ sw));
      bf16x8 v10 = *(const bf16x8*)(vbuf + (32 + ql) * 128 + (((tl * 4 + hi) << 4) ^ sw));
      bf16x8 v11 = *(const bf16x8*)(vbuf + (32 + ql) * 128 + (((tl * 4 + 2 + hi) << 4) ^ sw));
      __builtin_amdgcn_s_setprio(1);
      ot0 = MFMA32(v00, b0.v, ot0);
      ot0 = MFMA32(v01, b1.v, ot0);
      ot1 = MFMA32(v10, b0.v, ot1);
      ot1 = MFMA32(v11, b1.v, ot1);
      __builtin_amdgcn_s_setprio(0);
    }
    l += xhalf_sum(rs);
    __syncthreads();                 // all readers done with this buffer
    if (pf) {
      // write-late: HBM latency already hidden under compute; swizzled dest, linear source
#pragma unroll
      for (int i = 0; i < 8; ++i) {
        int s = i >> 1;
        char* sb = smem + s * 16384;
        if ((i & 1) == 0)
          *(uint4*)(sb + key8 * 128 + wchunk) = ld[i];
        else
          *(uint4*)(sb + 8192 + key8 * 128 + wchunk) = ld[i];
      }
    }
    __syncthreads();                 // writes visible to all waves
  }

  // ---- 4-way flash-merge (proven attn6 pattern, 3 writers + 1 merger per q-tile) ----
  float* part = (float*)smem;                       // [qt*3 + (ks-1)][64 d][33]
  float* merged = (float*)(smem + 51200);           // [2 qt][32 q][68]
  if (ks != 0) {
    if (hi == 0) { mls[qt][ks][0][ql] = m; mls[qt][ks][1][ql] = l; }
    float* pq = part + (size_t)(qt * 3 + (ks - 1)) * 64 * 33;
#pragma unroll
    for (int r = 0; r < 16; ++r) {
      int d = (r & 3) + 8 * (r >> 2) + 4 * hi;
      pq[d * 33 + ql] = ot0[r];
      pq[(d + 32) * 33 + ql] = ot1[r];
    }
  }
  __syncthreads();
  if (ks == 0) {
    float m1 = mls[qt][1][0][ql], m2 = mls[qt][2][0][ql], m3 = mls[qt][3][0][ql];
    float l1 = mls[qt][1][1][ql], l2 = mls[qt][2][1][ql], l3 = mls[qt][3][1][ql];
    float mg = fmaxf(fmaxf(m, m1), fmaxf(m2, m3));
    float e0 = __builtin_amdgcn_exp2f(m - mg);
    float e1 = __builtin_amdgcn_exp2f(m1 - mg);
    float e2 = __builtin_amdgcn_exp2f(m2 - mg);
    float e3 = __builtin_amdgcn_exp2f(m3 - mg);
    float inv = 1.0f / (l * e0 + l1 * e1 + l2 * e2 + l3 * e3);
    const float* p1 = part + (size_t)(qt * 3 + 0) * 64 * 33;
    const float* p2 = part + (size_t)(qt * 3 + 1) * 64 * 33;
    const float* p3 = part + (size_t)(qt * 3 + 2) * 64 * 33;
    float* mq = merged + qt * 32 * 68;
#pragma unroll
    for (int r = 0; r < 16; ++r) {
      int d = (r & 3) + 8 * (r >> 2) + 4 * hi;
      mq[ql * 68 + d] =
          (ot0[r] * e0 + p1[d * 33 + ql] * e1 + p2[d * 33 + ql] * e2 + p3[d * 33 + ql] * e3) * inv;
      mq[ql * 68 + 32 + d] =
          (ot1[r] * e0 + p1[(d + 32) * 33 + ql] * e1 + p2[(d + 32) * 33 + ql] * e2 +
           p3[(d + 32) * 33 + ql] * e3) * inv;
    }
  }
  __syncthreads();
  // ---- coalesced store: 512 threads cover 2 qt x 32 q x 8 chunks ----
  {
    int qt2 = t >> 8, row = (t >> 3) & 31, c8 = t & 7;
    const float* mq = merged + qt2 * 32 * 68 + row * 68 + c8 * 8;
    float4 f0 = *(const float4*)mq;
    float4 f1 = *(const float4*)(mq + 4);
    union { ushort us[8]; uint4 u4; } o;
    o.us[0] = f2b(f0.x); o.us[1] = f2b(f0.y); o.us[2] = f2b(f0.z); o.us[3] = f2b(f0.w);
    o.us[4] = f2b(f1.x); o.us[5] = f2b(f1.y); o.us[6] = f2b(f1.z); o.us[7] = f2b(f1.w);
    *(uint4*)(O + (size_t)(q0 + qt2 * 32 + row) * 1024 + h * 64 + c8 * 8) = o.u4;
  }
}

extern "C" void kernel_launch(void* const* d_in, const int* in_sizes, int n_in,
                              void* d_out, int out_size, void* d_ws, size_t ws_size,
                              hipStream_t stream) {
  (void)n_in; (void)out_size; (void)ws_size;
  const float* x    = (const float*)d_in[0];
  const float* Wqkv = (const float*)d_in[1];
  const float* bqkv = (const float*)d_in[2];
  const float* Wout = (const float*)d_in[3];
  const float* bout = (const float*)d_in[4];
  const float* rel  = (const float*)d_in[5];
  float* out = (float*)d_out;
  const int L = in_sizes[0] / 1024;  // 2048

  char* ws = (char*)d_ws;
  const size_t MB = 1024 * 1024;
  ushort* xb  = (ushort*)(ws);             // L*1024 bf16       (4 MB)
  ushort* w1t = (ushort*)(ws + 4 * MB);    // [3072][1024] bf16 (6 MB)
  ushort* w2t = (ushort*)(ws + 10 * MB);   // [1024][1024] bf16 (2 MB)
  ushort* Qsb = (ushort*)(ws + 36 * MB);   // [16][L][64] bf16  (4 MB)
  ushort* Kpb = (ushort*)(ws + 40 * MB);   // [16][L][64] bf16  (4 MB)
  ushort* Vtb = (ushort*)(ws + 44 * MB);   // [16][64][L] bf16  (4 MB)
  ushort* Ob  = (ushort*)(ws + 48 * MB);   // [L][1024] bf16    (4 MB)

  prep<<<dim3((L * 1024) / 1024 + 768 + 256), 256, 0, stream>>>(x, xb, Wqkv, w1t, Wout, w2t, L);
  gemm_qkv<<<dim3(3072 / 128, L / 128), 256, 0, stream>>>(xb, w1t, bqkv, rel, Qsb, Kpb, Vtb, L);
  attn11<<<dim3((L / 64) * 16), 512, 0, stream>>>(Qsb, Kpb, Vtb, Ob, L);
  gemm_dbuf<128, 64, true><<<dim3(1024 / 64, L / 128), 256, 0, stream>>>(Ob, w2t, out, bout, L, 1024, 1024);
}

// Round 13
// 91.575 us; speedup vs baseline: 1.4230x; 1.4230x over previous
//
#include <hip/hip_runtime.h>
#include <hip/hip_bf16.h>
#include <stdint.h>

typedef __attribute__((ext_vector_type(8))) __bf16 bf16x8;
typedef __attribute__((ext_vector_type(4))) float f32x4;
typedef __attribute__((ext_vector_type(16))) float f32x16;
typedef __attribute__((ext_vector_type(2))) uint32_t u32x2;

#define MFMA16(a, b, c) __builtin_amdgcn_mfma_f32_16x16x32_bf16(a, b, c, 0, 0, 0)
#define MFMA32(a, b, c) __builtin_amdgcn_mfma_f32_32x32x16_bf16(a, b, c, 0, 0, 0)

typedef const __attribute__((address_space(1))) uint32_t* gas_ptr;
typedef __attribute__((address_space(3))) uint32_t* lds_ptr;

static __device__ __forceinline__ ushort f2b(float f) {
  union { float f; uint32_t u; } x; x.f = f;
  uint32_t u = x.u + 0x7fffu + ((x.u >> 16) & 1u);
  return (ushort)(u >> 16);
}

static __device__ __forceinline__ void g2lds16(const void* g, void* l) {
  __builtin_amdgcn_global_load_lds((gas_ptr)(uintptr_t)g, (lds_ptr)(uintptr_t)l, 16, 0, 0);
}

// counted vmcnt (T4): leave prefetch in flight across the barrier
template <int N> static __device__ __forceinline__ void waitvm() {
  if constexpr (N == 0) asm volatile("s_waitcnt vmcnt(0)" ::: "memory");
  else if constexpr (N == 4) asm volatile("s_waitcnt vmcnt(4)" ::: "memory");
  else if constexpr (N == 6) asm volatile("s_waitcnt vmcnt(6)" ::: "memory");
  else if constexpr (N == 8) asm volatile("s_waitcnt vmcnt(8)" ::: "memory");
}

static __device__ __forceinline__ u32x2 plswap(uint32_t a, uint32_t b) {
  return __builtin_amdgcn_permlane32_swap(a, b, false, false);
}
static __device__ __forceinline__ float xhalf_max(float x) {
  u32x2 r = plswap(__float_as_uint(x), __float_as_uint(x));
  return fmaxf(__uint_as_float(r.x), __uint_as_float(r.y));
}
static __device__ __forceinline__ float xhalf_sum(float x) {
  u32x2 r = plswap(__float_as_uint(x), __float_as_uint(x));
  return __uint_as_float(r.x) + __uint_as_float(r.y);
}

// ---------------- prep: cvt x -> bf16, transpose Wqkv & Wout -> bf16 [N][K] ----------------
__global__ __launch_bounds__(256) void prep(const float* __restrict__ x, ushort* __restrict__ xb,
                                            const float* __restrict__ Wqkv, ushort* __restrict__ w1t,
                                            const float* __restrict__ Wout, ushort* __restrict__ w2t,
                                            int L) {
  const int b = blockIdx.x, t = threadIdx.x;
  const int ncvt = (L * 1024) / (256 * 4);  // 2048
  if (b < ncvt) {
    int i = (b * 256 + t) * 4;
    float4 v = *(const float4*)(x + i);
    ushort4 o;
    o.x = f2b(v.x); o.y = f2b(v.y); o.z = f2b(v.z); o.w = f2b(v.w);
    *(ushort4*)(xb + i) = o;
    return;
  }
  __shared__ ushort tile[64][65];
  const float* in; ushort* out; int N; int b2;
  const int K = 1024;
  if (b < ncvt + 768) { b2 = b - ncvt; N = 3072; in = Wqkv; out = w1t; }
  else                { b2 = b - ncvt - 768; N = 1024; in = Wout; out = w2t; }
  int nx = b2 % (N >> 6), ky = b2 / (N >> 6);
  int n0 = nx * 64, k0 = ky * 64;
#pragma unroll
  for (int i = 0; i < 16; ++i) {
    int idx = i * 256 + t;
    int r = idx >> 6, c = idx & 63;
    tile[r][c] = f2b(in[(size_t)(k0 + r) * N + n0 + c]);
  }
  __syncthreads();
#pragma unroll
  for (int i = 0; i < 16; ++i) {
    int idx = i * 256 + t;
    int r = idx >> 6, c = idx & 63;  // r = n index, c = k index
    out[(size_t)(n0 + r) * K + k0 + c] = tile[c][r];
  }
}

// ---------------- dbuf bf16 GEMM with counted vmcnt: C = A*Bt^T (+bias), fp32 C ----------------
template <int BM, int BN, bool BIAS>
__global__ __launch_bounds__(256) void gemm_dbuf(const ushort* __restrict__ A,
                                                 const ushort* __restrict__ Bt,
                                                 float* __restrict__ C,
                                                 const float* __restrict__ bias,
                                                 int M, int N, int K) {
  constexpr int WM = BM / 2, WN = BN / 2, MF = WM / 16, NF = WN / 16;
  constexpr int AI = BM / 32, BI = BN / 32;
  __shared__ ushort lA[2][BM * 64];
  __shared__ ushort lB[2][BN * 64];
  const int t = threadIdx.x, lane = t & 63;
  const int bm = blockIdx.y * BM, bn = blockIdx.x * BN;
  const int wid = t >> 6, wr = wid >> 1, wc = wid & 1;

  f32x4 acc[MF][NF] = {};

  auto STAGE = [&](int bb, int k0) {
#pragma unroll
    for (int i = 0; i < AI; ++i) {
      int ci = i * 256 + t;
      int r = ci >> 3, cs = ci & 7;
      int cg = (cs ^ (r & 7)) * 8;
      g2lds16(A + (size_t)(bm + r) * K + k0 + cg, (ushort*)lA[bb] + ci * 8);
    }
#pragma unroll
    for (int i = 0; i < BI; ++i) {
      int ci = i * 256 + t;
      int r = ci >> 3, cs = ci & 7;
      int cg = (cs ^ (r & 7)) * 8;
      g2lds16(Bt + (size_t)(bn + r) * K + k0 + cg, (ushort*)lB[bb] + ci * 8);
    }
  };

  STAGE(0, 0);
  const int NS = K >> 6;
  int buf = 0;
  for (int s = 0; s < NS; ++s) {
    if (s + 1 < NS) { STAGE(buf ^ 1, (s + 1) << 6); waitvm<AI + BI>(); }
    else            { waitvm<0>(); }
    __builtin_amdgcn_s_barrier();
    __builtin_amdgcn_sched_barrier(0);
#pragma unroll
    for (int kk = 0; kk < 2; ++kk) {
      bf16x8 af[MF], bfr[NF];
#pragma unroll
      for (int m = 0; m < MF; ++m) {
        int row = wr * WM + m * 16 + (lane & 15);
        int cb = kk * 64 + ((lane >> 4) << 4);
        int sw = cb ^ ((row & 7) << 4);
        af[m] = *(const bf16x8*)((const char*)lA[buf] + row * 128 + sw);
      }
#pragma unroll
      for (int n = 0; n < NF; ++n) {
        int row = wc * WN + n * 16 + (lane & 15);
        int cb = kk * 64 + ((lane >> 4) << 4);
        int sw = cb ^ ((row & 7) << 4);
        bfr[n] = *(const bf16x8*)((const char*)lB[buf] + row * 128 + sw);
      }
      __builtin_amdgcn_s_setprio(1);
#pragma unroll
      for (int m = 0; m < MF; ++m)
#pragma unroll
        for (int n = 0; n < NF; ++n) acc[m][n] = MFMA16(af[m], bfr[n], acc[m][n]);
      __builtin_amdgcn_s_setprio(0);
    }
    __builtin_amdgcn_s_barrier();      // readers done before next STAGE overwrites
    __builtin_amdgcn_sched_barrier(0);
    buf ^= 1;
  }
#pragma unroll
  for (int m = 0; m < MF; ++m) {
#pragma unroll
    for (int n = 0; n < NF; ++n) {
      int col = bn + wc * WN + n * 16 + (lane & 15);
      float b = BIAS ? bias[col] : 0.f;
#pragma unroll
      for (int r = 0; r < 4; ++r) {
        int row = bm + wr * WM + m * 16 + ((lane >> 4) << 2) + r;
        C[(size_t)row * N + col] = acc[m][n][r] + b;
      }
    }
  }
}

// ---------------- fused qkv GEMM (dbuf, counted vmcnt) ----------------
__global__ __launch_bounds__(256) void gemm_qkv(const ushort* __restrict__ A,
                                                const ushort* __restrict__ Bt,
                                                const float* __restrict__ bqkv,
                                                const float* __restrict__ rel,
                                                ushort* __restrict__ Qs,
                                                ushort* __restrict__ Kp,
                                                ushort* __restrict__ Vt, int M) {
  __shared__ ushort lA[2][128 * 64];
  __shared__ ushort lB[2][128 * 64];
  const int K = 1024;
  const int t = threadIdx.x, lane = t & 63;
  const int bm = blockIdx.y * 128, bn = blockIdx.x * 128;
  const int wid = t >> 6, wr = wid >> 1, wc = wid & 1;

  f32x4 acc[4][4] = {};

  auto STAGE = [&](int bb, int k0) {
#pragma unroll
    for (int i = 0; i < 4; ++i) {
      int ci = i * 256 + t;
      int r = ci >> 3, cs = ci & 7;
      int cg = (cs ^ (r & 7)) * 8;
      g2lds16(A + (size_t)(bm + r) * K + k0 + cg, (ushort*)lA[bb] + ci * 8);
      g2lds16(Bt + (size_t)(bn + r) * K + k0 + cg, (ushort*)lB[bb] + ci * 8);
    }
  };

  STAGE(0, 0);
  int buf = 0;
  for (int s = 0; s < 16; ++s) {
    if (s + 1 < 16) { STAGE(buf ^ 1, (s + 1) << 6); waitvm<8>(); }
    else            { waitvm<0>(); }
    __builtin_amdgcn_s_barrier();
    __builtin_amdgcn_sched_barrier(0);
#pragma unroll
    for (int kk = 0; kk < 2; ++kk) {
      bf16x8 af[4], bfr[4];
#pragma unroll
      for (int m = 0; m < 4; ++m) {
        int row = wr * 64 + m * 16 + (lane & 15);
        int cb = kk * 64 + ((lane >> 4) << 4);
        int sw = cb ^ ((row & 7) << 4);
        af[m] = *(const bf16x8*)((const char*)lA[buf] + row * 128 + sw);
      }
#pragma unroll
      for (int n = 0; n < 4; ++n) {
        int row = wc * 64 + n * 16 + (lane & 15);
        int cb = kk * 64 + ((lane >> 4) << 4);
        int sw = cb ^ ((row & 7) << 4);
        bfr[n] = *(const bf16x8*)((const char*)lB[buf] + row * 128 + sw);
      }
      __builtin_amdgcn_s_setprio(1);
#pragma unroll
      for (int m = 0; m < 4; ++m)
#pragma unroll
        for (int n = 0; n < 4; ++n) acc[m][n] = MFMA16(af[m], bfr[n], acc[m][n]);
      __builtin_amdgcn_s_setprio(0);
    }
    __builtin_amdgcn_s_barrier();
    __builtin_amdgcn_sched_barrier(0);
    buf ^= 1;
  }

  const int sec = bn >> 10;          // 0=Q, 1=K, 2=V
  const int cis_base = bn & 1023;
  if (sec < 2) {
    ushort* dst = (sec == 0) ? Qs : Kp;
    const float scale = (sec == 0) ? 0.18033688f : 1.0f;  // 0.125*log2(e) for Q
#pragma unroll
    for (int m = 0; m < 4; ++m) {
#pragma unroll
      for (int n = 0; n < 4; ++n) {
        int cis = cis_base + wc * 64 + n * 16 + (lane & 15);
        int hh = cis >> 6, dd = cis & 63;
        float b = bqkv[sec * 1024 + cis];
#pragma unroll
        for (int r = 0; r < 4; ++r) {
          int row = bm + wr * 64 + m * 16 + ((lane >> 4) << 2) + r;
          float v = acc[m][n][r] + b;
          if (sec == 1 && row > 0) v += rel[(size_t)(row - 1) * 64 + dd];
          dst[((size_t)hh * M + row) * 64 + dd] = f2b(v * scale);
        }
      }
    }
  } else {
    // V: bf16 into swizzled LDS [c][l], then coalesced transposed store.
    char* tb = (char*)lA;
#pragma unroll
    for (int m = 0; m < 4; ++m) {
#pragma unroll
      for (int n = 0; n < 4; ++n) {
        int cl = wc * 64 + n * 16 + (lane & 15);
        int ll = wr * 64 + m * 16 + ((lane >> 4) << 2);
        float b = bqkv[2048 + cis_base + cl];
        ushort4 w4;
        w4.x = f2b(acc[m][n][0] + b);
        w4.y = f2b(acc[m][n][1] + b);
        w4.z = f2b(acc[m][n][2] + b);
        w4.w = f2b(acc[m][n][3] + b);
        *(ushort4*)(tb + cl * 256 + ((ll * 2) ^ ((cl & 15) << 4))) = w4;
      }
    }
    __syncthreads();
#pragma unroll
    for (int ps = 0; ps < 8; ++ps) {
      int cl = ps * 16 + (t >> 4);
      int chunk = t & 15;
      uint4 rv = *(const uint4*)(tb + cl * 256 + ((chunk * 16) ^ ((cl & 15) << 4)));
      *(uint4*)(Vt + (size_t)(cis_base + cl) * M + bm + chunk * 8) = rv;
    }
  }
}

// ---------------- flash attention v12: attn8 + split-K across 2 blocks (flash-decoding) ----------------
// r12 lesson (repeat of r3): launch_bounds min-waves arg caps VGPR -> spills. NEVER again;
// occupancy comes from the grid. Grid 512 blocks (2 k-segments x 256): 4096 waves = 4/SIMD.
// Each block = attn8 verbatim over its 1024-key segment (2 streams x 512 keys, identical
// staging/softmax/MFMA); epilogue writes fp32 NUMERATOR partials + (m,l) to workspace.
// merge2 kernel combines the 2 segments into bf16 O.
__global__ __launch_bounds__(512) void attn12(const ushort* __restrict__ Qs,
                                              const ushort* __restrict__ Kp,
                                              const ushort* __restrict__ Vt,
                                              float* __restrict__ Opart,
                                              float* __restrict__ ml, int L) {
  __shared__ char smem[69632];
  __shared__ float mls[4][2][32];
  const int bid = blockIdx.x;
  const int h = (bid & 7) * 2 + ((bid >> 7) & 1);  // XCD (bid%8) serves heads {2c,2c+1}
  const int q0 = ((bid >> 3) & 15) * 128;
  const int kseg = bid >> 8;
  const int t = threadIdx.x, lane = t & 63, w = t >> 6;
  const int qt = w & 3, ks = w >> 2;
  const int ql = lane & 31, hi = lane >> 5;
  const int sw = (ql & 7) << 4;
  const ushort* kh = Kp + (size_t)h * L * 64;
  const ushort* vh = Vt + (size_t)h * 64 * L;
  const int span = L >> 2;             // 512 keys per stream
  const int base_k = kseg * (L >> 1);
  const int NT = span >> 6;            // 8 tiles

  bf16x8 qf[4];
  {
    const ushort* qrow = Qs + ((size_t)h * L + q0 + qt * 32 + ql) * 64 + hi * 8;
#pragma unroll
    for (int c = 0; c < 4; ++c) qf[c] = *(const bf16x8*)(qrow + c * 16);
  }

  f32x16 ot0 = {}, ot1 = {};
  float m = -1e30f, l = 0.f;

  auto STAGE = [&](int bb, int tt) {
    char* base = smem + bb * 32768;
#pragma unroll
    for (int s = 0; s < 2; ++s) {
      int kb = base_k + s * span + tt * 64;
      char* sb = base + s * 16384;
      {
        int key = t >> 3, pch = t & 7;
        g2lds16(kh + (((size_t)(kb + key)) << 6) + ((pch ^ (key & 7)) << 3), sb + t * 16);
      }
      {
        int d = t >> 3, pch = t & 7;
        g2lds16(vh + (size_t)d * L + kb + ((pch ^ (d & 7)) << 3), sb + 8192 + t * 16);
      }
    }
  };

  STAGE(0, 0);
  int buf = 0;
  for (int tt = 0; tt < NT; ++tt) {
    if (tt + 1 < NT) { STAGE(buf ^ 1, tt + 1); waitvm<4>(); }
    else             { waitvm<0>(); }
    __builtin_amdgcn_s_barrier();
    __builtin_amdgcn_sched_barrier(0);
    const char* kbuf = smem + buf * 32768 + ks * 16384;
    const char* vbuf = kbuf + 8192;
    f32x16 s0 = {}, s1 = {};
    __builtin_amdgcn_s_setprio(1);
#pragma unroll
    for (int c = 0; c < 4; ++c) {
      bf16x8 k0 = *(const bf16x8*)(kbuf + ql * 128 + (((2 * c + hi) << 4) ^ sw));
      bf16x8 k1 = *(const bf16x8*)(kbuf + (32 + ql) * 128 + (((2 * c + hi) << 4) ^ sw));
      s0 = MFMA32(k0, qf[c], s0);
      s1 = MFMA32(k1, qf[c], s1);
    }
    __builtin_amdgcn_s_setprio(0);
    float mx = fmaxf(s0[0], s1[0]);
#pragma unroll
    for (int i = 1; i < 16; ++i) mx = fmaxf(fmaxf(s0[i], s1[i]), mx);
    mx = xhalf_max(mx);
    if (!__all(mx - m <= 8.0f)) {  // defer-max
      float mn = fmaxf(m, mx);
      float sc = __builtin_amdgcn_exp2f(m - mn);
      m = mn;
      l *= sc;
      ot0 = ot0 * sc;
      ot1 = ot1 * sc;
    }
    float rs = 0.f;
#pragma unroll
    for (int tl = 0; tl < 2; ++tl) {
      f32x16 s = tl ? s1 : s0;
      float p[16];
      float r0 = 0.f, r1 = 0.f;
#pragma unroll
      for (int i = 0; i < 16; i += 2) {
        p[i] = __builtin_amdgcn_exp2f(s[i] - m);
        p[i + 1] = __builtin_amdgcn_exp2f(s[i + 1] - m);
        r0 += p[i];
        r1 += p[i + 1];
      }
      rs += r0 + r1;
      uint32_t a[8];
#pragma unroll
      for (int i = 0; i < 8; ++i) {
        uint32_t r;
        asm("v_cvt_pk_bf16_f32 %0, %1, %2" : "=v"(r) : "v"(p[2 * i]), "v"(p[2 * i + 1]));
        a[i] = r;
      }
      u32x2 s02 = plswap(a[0], a[2]);
      u32x2 s13 = plswap(a[1], a[3]);
      u32x2 s46 = plswap(a[4], a[6]);
      u32x2 s57 = plswap(a[5], a[7]);
      union { uint32_t u[4]; bf16x8 v; } b0, b1;
      b0.u[0] = s02.x; b0.u[1] = s13.x; b0.u[2] = s02.y; b0.u[3] = s13.y;
      b1.u[0] = s46.x; b1.u[1] = s57.x; b1.u[2] = s46.y; b1.u[3] = s57.y;
      bf16x8 v00 = *(const bf16x8*)(vbuf + ql * 128 + (((tl * 4 + hi) << 4) ^ sw));
      bf16x8 v01 = *(const bf16x8*)(vbuf + ql * 128 + (((tl * 4 + 2 + hi) << 4) ^ sw));
      bf16x8 v10 = *(const bf16x8*)(vbuf + (32 + ql) * 128 + (((tl * 4 + hi) << 4) ^ sw));
      bf16x8 v11 = *(const bf16x8*)(vbuf + (32 + ql) * 128 + (((tl * 4 + 2 + hi) << 4) ^ sw));
      __builtin_amdgcn_s_setprio(1);
      ot0 = MFMA32(v00, b0.v, ot0);
      ot0 = MFMA32(v01, b1.v, ot0);
      ot1 = MFMA32(v10, b0.v, ot1);
      ot1 = MFMA32(v11, b1.v, ot1);
      __builtin_amdgcn_s_setprio(0);
    }
    l += xhalf_sum(rs);
    __builtin_amdgcn_s_barrier();      // readers done before next STAGE overwrites
    __builtin_amdgcn_sched_barrier(0);
    buf ^= 1;
  }

  // ---- 2-way in-block flash-merge -> fp32 numerator partial + (m,l) to global ----
  float* part = (float*)smem;                        // [4 qt][64 d][33]
  float* merged = (float*)(smem + 4 * 64 * 33 * 4);  // [4 qt][32 q][68]
  if (ks == 1) {
    if (hi == 0) { mls[qt][0][ql] = m; mls[qt][1][ql] = l; }
    float* pq = part + qt * 64 * 33;
#pragma unroll
    for (int r = 0; r < 16; ++r) {
      int d = (r & 3) + 8 * (r >> 2) + 4 * hi;
      pq[d * 33 + ql] = ot0[r];
      pq[(d + 32) * 33 + ql] = ot1[r];
    }
  }
  __syncthreads();
  if (ks == 0) {
    float m1 = mls[qt][0][ql], l1 = mls[qt][1][ql];
    float mg = fmaxf(m, m1);
    float e0 = __builtin_amdgcn_exp2f(m - mg);
    float e1 = __builtin_amdgcn_exp2f(m1 - mg);
    float lg = l * e0 + l1 * e1;
    if (hi == 0) {
      size_t rr = (size_t)(kseg * 16 + h) * L + q0 + qt * 32 + ql;
      ml[rr * 2] = mg;
      ml[rr * 2 + 1] = lg;
    }
    float* pq = part + qt * 64 * 33;
    float* mq = merged + qt * 32 * 68;
#pragma unroll
    for (int r = 0; r < 16; ++r) {
      int d = (r & 3) + 8 * (r >> 2) + 4 * hi;
      mq[ql * 68 + d] = ot0[r] * e0 + pq[d * 33 + ql] * e1;          // numerator only
      mq[ql * 68 + 32 + d] = ot1[r] * e0 + pq[(d + 32) * 33 + ql] * e1;
    }
  }
  __syncthreads();
  // ---- fp32 partial store: [kseg][h][q][64] ----
#pragma unroll
  for (int pss = 0; pss < 2; ++pss) {
    int id = pss * 512 + t;
    int qt2 = id >> 8, row = (id >> 3) & 31, c8 = id & 7;
    const float* mq = merged + qt2 * 32 * 68 + row * 68 + c8 * 8;
    float4 f0 = *(const float4*)mq;
    float4 f1 = *(const float4*)(mq + 4);
    float* dst = Opart + ((size_t)(kseg * 16 + h) * L + q0 + qt2 * 32 + row) * 64 + c8 * 8;
    *(float4*)dst = f0;
    *(float4*)(dst + 4) = f1;
  }
}

// ---------------- merge2: combine the 2 k-segment partials -> bf16 O ----------------
__global__ __launch_bounds__(256) void merge2(const float* __restrict__ Opart,
                                              const float* __restrict__ ml,
                                              ushort* __restrict__ O, int L) {
  int idx = blockIdx.x * 256 + threadIdx.x;   // 16*L*8 total
  int c8 = idx & 7;
  int row = idx >> 3;                         // h*L + q
  int h = row >> 11, q = row & (L - 1);       // L = 2048
  float m0 = ml[(size_t)row * 2], l0 = ml[(size_t)row * 2 + 1];
  float m1 = ml[((size_t)16 * L + row) * 2], l1 = ml[((size_t)16 * L + row) * 2 + 1];
  float M = fmaxf(m0, m1);
  float w0 = __builtin_amdgcn_exp2f(m0 - M);
  float w1 = __builtin_amdgcn_exp2f(m1 - M);
  float inv = 1.0f / (l0 * w0 + l1 * w1);
  const float* p0 = Opart + (size_t)row * 64 + c8 * 8;
  const float* p1 = Opart + ((size_t)16 * L + row) * 64 + c8 * 8;
  float4 a0 = *(const float4*)p0, a1 = *(const float4*)(p0 + 4);
  float4 b0 = *(const float4*)p1, b1 = *(const float4*)(p1 + 4);
  union { ushort us[8]; uint4 u4; } o;
  o.us[0] = f2b((a0.x * w0 + b0.x * w1) * inv);
  o.us[1] = f2b((a0.y * w0 + b0.y * w1) * inv);
  o.us[2] = f2b((a0.z * w0 + b0.z * w1) * inv);
  o.us[3] = f2b((a0.w * w0 + b0.w * w1) * inv);
  o.us[4] = f2b((a1.x * w0 + b1.x * w1) * inv);
  o.us[5] = f2b((a1.y * w0 + b1.y * w1) * inv);
  o.us[6] = f2b((a1.z * w0 + b1.z * w1) * inv);
  o.us[7] = f2b((a1.w * w0 + b1.w * w1) * inv);
  *(uint4*)(O + (size_t)q * 1024 + h * 64 + c8 * 8) = o.u4;
}

extern "C" void kernel_launch(void* const* d_in, const int* in_sizes, int n_in,
                              void* d_out, int out_size, void* d_ws, size_t ws_size,
                              hipStream_t stream) {
  (void)n_in; (void)out_size; (void)ws_size;
  const float* x    = (const float*)d_in[0];
  const float* Wqkv = (const float*)d_in[1];
  const float* bqkv = (const float*)d_in[2];
  const float* Wout = (const float*)d_in[3];
  const float* bout = (const float*)d_in[4];
  const float* rel  = (const float*)d_in[5];
  float* out = (float*)d_out;
  const int L = in_sizes[0] / 1024;  // 2048

  char* ws = (char*)d_ws;
  const size_t MB = 1024 * 1024;
  ushort* xb    = (ushort*)(ws);             // L*1024 bf16       (4 MB)
  ushort* w1t   = (ushort*)(ws + 4 * MB);    // [3072][1024] bf16 (6 MB)
  ushort* w2t   = (ushort*)(ws + 10 * MB);   // [1024][1024] bf16 (2 MB)
  float*  Opart = (float*)(ws + 12 * MB);    // [2][16][L][64] f32 (16 MB, reuses old qkv hole)
  float*  mlb   = (float*)(ws + 28 * MB);    // [2][16*L][2] f32   (0.5 MB)
  ushort* Qsb   = (ushort*)(ws + 36 * MB);   // [16][L][64] bf16  (4 MB)
  ushort* Kpb   = (ushort*)(ws + 40 * MB);   // [16][L][64] bf16  (4 MB)
  ushort* Vtb   = (ushort*)(ws + 44 * MB);   // [16][64][L] bf16  (4 MB)
  ushort* Ob    = (ushort*)(ws + 48 * MB);   // [L][1024] bf16    (4 MB)

  prep<<<dim3((L * 1024) / 1024 + 768 + 256), 256, 0, stream>>>(x, xb, Wqkv, w1t, Wout, w2t, L);
  gemm_qkv<<<dim3(3072 / 128, L / 128), 256, 0, stream>>>(xb, w1t, bqkv, rel, Qsb, Kpb, Vtb, L);
  attn12<<<dim3((L / 128) * 16 * 2), 512, 0, stream>>>(Qsb, Kpb, Vtb, Opart, mlb, L);
  merge2<<<dim3(16 * L * 8 / 256), 256, 0, stream>>>(Opart, mlb, Ob, L);
  gemm_dbuf<128, 64, true><<<dim3(1024 / 64, L / 128), 256, 0, stream>>>(Ob, w2t, out, bout, L, 1024, 1024);
}

// Round 14
// 82.019 us; speedup vs baseline: 1.5888x; 1.1165x over previous
//
#include <hip/hip_runtime.h>
#include <hip/hip_bf16.h>
#include <stdint.h>

typedef __attribute__((ext_vector_type(8))) __bf16 bf16x8;
typedef __attribute__((ext_vector_type(4))) float f32x4;
typedef __attribute__((ext_vector_type(16))) float f32x16;
typedef __attribute__((ext_vector_type(2))) uint32_t u32x2;

#define MFMA16(a, b, c) __builtin_amdgcn_mfma_f32_16x16x32_bf16(a, b, c, 0, 0, 0)
#define MFMA32(a, b, c) __builtin_amdgcn_mfma_f32_32x32x16_bf16(a, b, c, 0, 0, 0)

typedef const __attribute__((address_space(1))) uint32_t* gas_ptr;
typedef __attribute__((address_space(3))) uint32_t* lds_ptr;

static __device__ __forceinline__ ushort f2b(float f) {
  union { float f; uint32_t u; } x; x.f = f;
  uint32_t u = x.u + 0x7fffu + ((x.u >> 16) & 1u);
  return (ushort)(u >> 16);
}

static __device__ __forceinline__ void g2lds16(const void* g, void* l) {
  __builtin_amdgcn_global_load_lds((gas_ptr)(uintptr_t)g, (lds_ptr)(uintptr_t)l, 16, 0, 0);
}

// counted vmcnt (T4): leave prefetch in flight across the barrier
template <int N> static __device__ __forceinline__ void waitvm() {
  if constexpr (N == 0) asm volatile("s_waitcnt vmcnt(0)" ::: "memory");
  else if constexpr (N == 4) asm volatile("s_waitcnt vmcnt(4)" ::: "memory");
  else if constexpr (N == 6) asm volatile("s_waitcnt vmcnt(6)" ::: "memory");
  else if constexpr (N == 8) asm volatile("s_waitcnt vmcnt(8)" ::: "memory");
}

static __device__ __forceinline__ u32x2 plswap(uint32_t a, uint32_t b) {
  return __builtin_amdgcn_permlane32_swap(a, b, false, false);
}
static __device__ __forceinline__ float xhalf_max(float x) {
  u32x2 r = plswap(__float_as_uint(x), __float_as_uint(x));
  return fmaxf(__uint_as_float(r.x), __uint_as_float(r.y));
}
static __device__ __forceinline__ float xhalf_sum(float x) {
  u32x2 r = plswap(__float_as_uint(x), __float_as_uint(x));
  return __uint_as_float(r.x) + __uint_as_float(r.y);
}

// ---------------- prep: cvt x -> bf16, transpose Wqkv & Wout -> bf16 [N][K] ----------------
__global__ __launch_bounds__(256) void prep(const float* __restrict__ x, ushort* __restrict__ xb,
                                            const float* __restrict__ Wqkv, ushort* __restrict__ w1t,
                                            const float* __restrict__ Wout, ushort* __restrict__ w2t,
                                            int L) {
  const int b = blockIdx.x, t = threadIdx.x;
  const int ncvt = (L * 1024) / (256 * 4);  // 2048
  if (b < ncvt) {
    int i = (b * 256 + t) * 4;
    float4 v = *(const float4*)(x + i);
    ushort4 o;
    o.x = f2b(v.x); o.y = f2b(v.y); o.z = f2b(v.z); o.w = f2b(v.w);
    *(ushort4*)(xb + i) = o;
    return;
  }
  __shared__ ushort tile[64][65];
  const float* in; ushort* out; int N; int b2;
  const int K = 1024;
  if (b < ncvt + 768) { b2 = b - ncvt; N = 3072; in = Wqkv; out = w1t; }
  else                { b2 = b - ncvt - 768; N = 1024; in = Wout; out = w2t; }
  int nx = b2 % (N >> 6), ky = b2 / (N >> 6);
  int n0 = nx * 64, k0 = ky * 64;
#pragma unroll
  for (int i = 0; i < 16; ++i) {
    int idx = i * 256 + t;
    int r = idx >> 6, c = idx & 63;
    tile[r][c] = f2b(in[(size_t)(k0 + r) * N + n0 + c]);
  }
  __syncthreads();
#pragma unroll
  for (int i = 0; i < 16; ++i) {
    int idx = i * 256 + t;
    int r = idx >> 6, c = idx & 63;  // r = n index, c = k index
    out[(size_t)(n0 + r) * K + k0 + c] = tile[c][r];
  }
}

// ---------------- dbuf bf16 GEMM with counted vmcnt: C = A*Bt^T (+bias), fp32 C ----------------
template <int BM, int BN, bool BIAS>
__global__ __launch_bounds__(256) void gemm_dbuf(const ushort* __restrict__ A,
                                                 const ushort* __restrict__ Bt,
                                                 float* __restrict__ C,
                                                 const float* __restrict__ bias,
                                                 int M, int N, int K) {
  constexpr int WM = BM / 2, WN = BN / 2, MF = WM / 16, NF = WN / 16;
  constexpr int AI = BM / 32, BI = BN / 32;
  __shared__ ushort lA[2][BM * 64];
  __shared__ ushort lB[2][BN * 64];
  const int t = threadIdx.x, lane = t & 63;
  const int bm = blockIdx.y * BM, bn = blockIdx.x * BN;
  const int wid = t >> 6, wr = wid >> 1, wc = wid & 1;

  f32x4 acc[MF][NF] = {};

  auto STAGE = [&](int bb, int k0) {
#pragma unroll
    for (int i = 0; i < AI; ++i) {
      int ci = i * 256 + t;
      int r = ci >> 3, cs = ci & 7;
      int cg = (cs ^ (r & 7)) * 8;
      g2lds16(A + (size_t)(bm + r) * K + k0 + cg, (ushort*)lA[bb] + ci * 8);
    }
#pragma unroll
    for (int i = 0; i < BI; ++i) {
      int ci = i * 256 + t;
      int r = ci >> 3, cs = ci & 7;
      int cg = (cs ^ (r & 7)) * 8;
      g2lds16(Bt + (size_t)(bn + r) * K + k0 + cg, (ushort*)lB[bb] + ci * 8);
    }
  };

  STAGE(0, 0);
  const int NS = K >> 6;
  int buf = 0;
  for (int s = 0; s < NS; ++s) {
    if (s + 1 < NS) { STAGE(buf ^ 1, (s + 1) << 6); waitvm<AI + BI>(); }
    else            { waitvm<0>(); }
    __builtin_amdgcn_s_barrier();
    __builtin_amdgcn_sched_barrier(0);
#pragma unroll
    for (int kk = 0; kk < 2; ++kk) {
      bf16x8 af[MF], bfr[NF];
#pragma unroll
      for (int m = 0; m < MF; ++m) {
        int row = wr * WM + m * 16 + (lane & 15);
        int cb = kk * 64 + ((lane >> 4) << 4);
        int sw = cb ^ ((row & 7) << 4);
        af[m] = *(const bf16x8*)((const char*)lA[buf] + row * 128 + sw);
      }
#pragma unroll
      for (int n = 0; n < NF; ++n) {
        int row = wc * WN + n * 16 + (lane & 15);
        int cb = kk * 64 + ((lane >> 4) << 4);
        int sw = cb ^ ((row & 7) << 4);
        bfr[n] = *(const bf16x8*)((const char*)lB[buf] + row * 128 + sw);
      }
      __builtin_amdgcn_s_setprio(1);
#pragma unroll
      for (int m = 0; m < MF; ++m)
#pragma unroll
        for (int n = 0; n < NF; ++n) acc[m][n] = MFMA16(af[m], bfr[n], acc[m][n]);
      __builtin_amdgcn_s_setprio(0);
    }
    __builtin_amdgcn_s_barrier();      // readers done before next STAGE overwrites
    __builtin_amdgcn_sched_barrier(0);
    buf ^= 1;
  }
#pragma unroll
  for (int m = 0; m < MF; ++m) {
#pragma unroll
    for (int n = 0; n < NF; ++n) {
      int col = bn + wc * WN + n * 16 + (lane & 15);
      float b = BIAS ? bias[col] : 0.f;
#pragma unroll
      for (int r = 0; r < 4; ++r) {
        int row = bm + wr * WM + m * 16 + ((lane >> 4) << 2) + r;
        C[(size_t)row * N + col] = acc[m][n][r] + b;
      }
    }
  }
}

// ---------------- fused qkv GEMM (dbuf, counted vmcnt) ----------------
__global__ __launch_bounds__(256) void gemm_qkv(const ushort* __restrict__ A,
                                                const ushort* __restrict__ Bt,
                                                const float* __restrict__ bqkv,
                                                const float* __restrict__ rel,
                                                ushort* __restrict__ Qs,
                                                ushort* __restrict__ Kp,
                                                ushort* __restrict__ Vt, int M) {
  __shared__ ushort lA[2][128 * 64];
  __shared__ ushort lB[2][128 * 64];
  const int K = 1024;
  const int t = threadIdx.x, lane = t & 63;
  const int bm = blockIdx.y * 128, bn = blockIdx.x * 128;
  const int wid = t >> 6, wr = wid >> 1, wc = wid & 1;

  f32x4 acc[4][4] = {};

  auto STAGE = [&](int bb, int k0) {
#pragma unroll
    for (int i = 0; i < 4; ++i) {
      int ci = i * 256 + t;
      int r = ci >> 3, cs = ci & 7;
      int cg = (cs ^ (r & 7)) * 8;
      g2lds16(A + (size_t)(bm + r) * K + k0 + cg, (ushort*)lA[bb] + ci * 8);
      g2lds16(Bt + (size_t)(bn + r) * K + k0 + cg, (ushort*)lB[bb] + ci * 8);
    }
  };

  STAGE(0, 0);
  int buf = 0;
  for (int s = 0; s < 16; ++s) {
    if (s + 1 < 16) { STAGE(buf ^ 1, (s + 1) << 6); waitvm<8>(); }
    else            { waitvm<0>(); }
    __builtin_amdgcn_s_barrier();
    __builtin_amdgcn_sched_barrier(0);
#pragma unroll
    for (int kk = 0; kk < 2; ++kk) {
      bf16x8 af[4], bfr[4];
#pragma unroll
      for (int m = 0; m < 4; ++m) {
        int row = wr * 64 + m * 16 + (lane & 15);
        int cb = kk * 64 + ((lane >> 4) << 4);
        int sw = cb ^ ((row & 7) << 4);
        af[m] = *(const bf16x8*)((const char*)lA[buf] + row * 128 + sw);
      }
#pragma unroll
      for (int n = 0; n < 4; ++n) {
        int row = wc * 64 + n * 16 + (lane & 15);
        int cb = kk * 64 + ((lane >> 4) << 4);
        int sw = cb ^ ((row & 7) << 4);
        bfr[n] = *(const bf16x8*)((const char*)lB[buf] + row * 128 + sw);
      }
      __builtin_amdgcn_s_setprio(1);
#pragma unroll
      for (int m = 0; m < 4; ++m)
#pragma unroll
        for (int n = 0; n < 4; ++n) acc[m][n] = MFMA16(af[m], bfr[n], acc[m][n]);
      __builtin_amdgcn_s_setprio(0);
    }
    __builtin_amdgcn_s_barrier();
    __builtin_amdgcn_sched_barrier(0);
    buf ^= 1;
  }

  const int sec = bn >> 10;          // 0=Q, 1=K, 2=V
  const int cis_base = bn & 1023;
  if (sec < 2) {
    ushort* dst = (sec == 0) ? Qs : Kp;
    const float scale = (sec == 0) ? 0.18033688f : 1.0f;  // 0.125*log2(e) for Q
#pragma unroll
    for (int m = 0; m < 4; ++m) {
#pragma unroll
      for (int n = 0; n < 4; ++n) {
        int cis = cis_base + wc * 64 + n * 16 + (lane & 15);
        int hh = cis >> 6, dd = cis & 63;
        float b = bqkv[sec * 1024 + cis];
#pragma unroll
        for (int r = 0; r < 4; ++r) {
          int row = bm + wr * 64 + m * 16 + ((lane >> 4) << 2) + r;
          float v = acc[m][n][r] + b;
          if (sec == 1 && row > 0) v += rel[(size_t)(row - 1) * 64 + dd];
          dst[((size_t)hh * M + row) * 64 + dd] = f2b(v * scale);
        }
      }
    }
  } else {
    // V: bf16 into swizzled LDS [c][l], then coalesced transposed store.
    char* tb = (char*)lA;
#pragma unroll
    for (int m = 0; m < 4; ++m) {
#pragma unroll
      for (int n = 0; n < 4; ++n) {
        int cl = wc * 64 + n * 16 + (lane & 15);
        int ll = wr * 64 + m * 16 + ((lane >> 4) << 2);
        float b = bqkv[2048 + cis_base + cl];
        ushort4 w4;
        w4.x = f2b(acc[m][n][0] + b);
        w4.y = f2b(acc[m][n][1] + b);
        w4.z = f2b(acc[m][n][2] + b);
        w4.w = f2b(acc[m][n][3] + b);
        *(ushort4*)(tb + cl * 256 + ((ll * 2) ^ ((cl & 15) << 4))) = w4;
      }
    }
    __syncthreads();
#pragma unroll
    for (int ps = 0; ps < 8; ++ps) {
      int cl = ps * 16 + (t >> 4);
      int chunk = t & 15;
      uint4 rv = *(const uint4*)(tb + cl * 256 + ((chunk * 16) ^ ((cl & 15) << 4)));
      *(uint4*)(Vt + (size_t)(cis_base + cl) * M + bm + chunk * 8) = rv;
    }
  }
}

// ---------------- flash attention v8 (r9 best): 8 waves, 4 qt x 2 streams, T4+T5 ----------------
// r13 lesson: split-K across blocks (4096 waves) bought nothing -> attn8 is NOT
// latency-bound at 2 waves/SIMD; it is at its structural issue-throughput ceiling.
// r3/r12 lesson: never pass a launch_bounds min-waves arg (VGPR cap -> spills).
// r10/r11 lesson: >=128KB static LDS per block fails to launch; 68KB-class works.
__global__ __launch_bounds__(512) void attn8(const ushort* __restrict__ Qs,
                                             const ushort* __restrict__ Kp,
                                             const ushort* __restrict__ Vt,
                                             ushort* __restrict__ O, int L) {
  __shared__ char smem[69632];   // 2 buf x 2 stream x (K 8KB + V 8KB) = 64KB; merge aliased
  __shared__ float mls[4][2][32];
  const int bid = blockIdx.x;
  const int h = (bid & 7) * 2 + (bid >> 7);      // XCD (bid%8) serves heads {2c,2c+1}
  const int q0 = ((bid >> 3) & 15) * 128;
  const int t = threadIdx.x, lane = t & 63, w = t >> 6;
  const int qt = w & 3, ks = w >> 2;
  const int ql = lane & 31, hi = lane >> 5;
  const int sw = (ql & 7) << 4;
  const ushort* kh = Kp + (size_t)h * L * 64;
  const ushort* vh = Vt + (size_t)h * 64 * L;
  const int half = L >> 1;
  const int NT = half >> 6;

  bf16x8 qf[4];
  {
    const ushort* qrow = Qs + ((size_t)h * L + q0 + qt * 32 + ql) * 64 + hi * 8;
#pragma unroll
    for (int c = 0; c < 4; ++c) qf[c] = *(const bf16x8*)(qrow + c * 16);
  }

  f32x16 ot0 = {}, ot1 = {};
  float m = -1e30f, l = 0.f;

  auto STAGE = [&](int bb, int tt) {
    char* base = smem + bb * 32768;
#pragma unroll
    for (int s = 0; s < 2; ++s) {
      int kb = s * half + tt * 64;
      char* sb = base + s * 16384;
      {
        int key = t >> 3, pch = t & 7;
        g2lds16(kh + (((size_t)(kb + key)) << 6) + ((pch ^ (key & 7)) << 3), sb + t * 16);
      }
      {
        int d = t >> 3, pch = t & 7;
        g2lds16(vh + (size_t)d * L + kb + ((pch ^ (d & 7)) << 3), sb + 8192 + t * 16);
      }
    }
  };

  STAGE(0, 0);
  int buf = 0;
  for (int tt = 0; tt < NT; ++tt) {
    if (tt + 1 < NT) { STAGE(buf ^ 1, tt + 1); waitvm<4>(); }
    else             { waitvm<0>(); }
    __builtin_amdgcn_s_barrier();
    __builtin_amdgcn_sched_barrier(0);
    const char* kbuf = smem + buf * 32768 + ks * 16384;
    const char* vbuf = kbuf + 8192;
    f32x16 s0 = {}, s1 = {};
    __builtin_amdgcn_s_setprio(1);
#pragma unroll
    for (int c = 0; c < 4; ++c) {
      bf16x8 k0 = *(const bf16x8*)(kbuf + ql * 128 + (((2 * c + hi) << 4) ^ sw));
      bf16x8 k1 = *(const bf16x8*)(kbuf + (32 + ql) * 128 + (((2 * c + hi) << 4) ^ sw));
      s0 = MFMA32(k0, qf[c], s0);
      s1 = MFMA32(k1, qf[c], s1);
    }
    __builtin_amdgcn_s_setprio(0);
    float mx = fmaxf(s0[0], s1[0]);
#pragma unroll
    for (int i = 1; i < 16; ++i) mx = fmaxf(fmaxf(s0[i], s1[i]), mx);
    mx = xhalf_max(mx);
    if (!__all(mx - m <= 8.0f)) {  // defer-max
      float mn = fmaxf(m, mx);
      float sc = __builtin_amdgcn_exp2f(m - mn);
      m = mn;
      l *= sc;
      ot0 = ot0 * sc;
      ot1 = ot1 * sc;
    }
    float rs = 0.f;
#pragma unroll
    for (int tl = 0; tl < 2; ++tl) {
      f32x16 s = tl ? s1 : s0;
      float p[16];
      float r0 = 0.f, r1 = 0.f;
#pragma unroll
      for (int i = 0; i < 16; i += 2) {
        p[i] = __builtin_amdgcn_exp2f(s[i] - m);
        p[i + 1] = __builtin_amdgcn_exp2f(s[i + 1] - m);
        r0 += p[i];
        r1 += p[i + 1];
      }
      rs += r0 + r1;
      uint32_t a[8];
#pragma unroll
      for (int i = 0; i < 8; ++i) {
        uint32_t r;
        asm("v_cvt_pk_bf16_f32 %0, %1, %2" : "=v"(r) : "v"(p[2 * i]), "v"(p[2 * i + 1]));
        a[i] = r;
      }
      u32x2 s02 = plswap(a[0], a[2]);
      u32x2 s13 = plswap(a[1], a[3]);
      u32x2 s46 = plswap(a[4], a[6]);
      u32x2 s57 = plswap(a[5], a[7]);
      union { uint32_t u[4]; bf16x8 v; } b0, b1;
      b0.u[0] = s02.x; b0.u[1] = s13.x; b0.u[2] = s02.y; b0.u[3] = s13.y;
      b1.u[0] = s46.x; b1.u[1] = s57.x; b1.u[2] = s46.y; b1.u[3] = s57.y;
      bf16x8 v00 = *(const bf16x8*)(vbuf + ql * 128 + (((tl * 4 + hi) << 4) ^ sw));
      bf16x8 v01 = *(const bf16x8*)(vbuf + ql * 128 + (((tl * 4 + 2 + hi) << 4) ^ sw));
      bf16x8 v10 = *(const bf16x8*)(vbuf + (32 + ql) * 128 + (((tl * 4 + hi) << 4) ^ sw));
      bf16x8 v11 = *(const bf16x8*)(vbuf + (32 + ql) * 128 + (((tl * 4 + 2 + hi) << 4) ^ sw));
      __builtin_amdgcn_s_setprio(1);
      ot0 = MFMA32(v00, b0.v, ot0);
      ot0 = MFMA32(v01, b1.v, ot0);
      ot1 = MFMA32(v10, b0.v, ot1);
      ot1 = MFMA32(v11, b1.v, ot1);
      __builtin_amdgcn_s_setprio(0);
    }
    l += xhalf_sum(rs);
    __builtin_amdgcn_s_barrier();      // readers done before next STAGE overwrites
    __builtin_amdgcn_sched_barrier(0);
    buf ^= 1;
  }

  // ---- 2-way flash-merge per q-tile (LDS aliased over stage buffers) ----
  float* part = (float*)smem;                        // [4 qt][64 d][33]
  float* merged = (float*)(smem + 4 * 64 * 33 * 4);  // [4 qt][32 q][68]
  if (ks == 1) {
    if (hi == 0) { mls[qt][0][ql] = m; mls[qt][1][ql] = l; }
    float* pq = part + qt * 64 * 33;
#pragma unroll
    for (int r = 0; r < 16; ++r) {
      int d = (r & 3) + 8 * (r >> 2) + 4 * hi;
      pq[d * 33 + ql] = ot0[r];
      pq[(d + 32) * 33 + ql] = ot1[r];
    }
  }
  __syncthreads();
  if (ks == 0) {
    float m1 = mls[qt][0][ql], l1 = mls[qt][1][ql];
    float mg = fmaxf(m, m1);
    float e0 = __builtin_amdgcn_exp2f(m - mg);
    float e1 = __builtin_amdgcn_exp2f(m1 - mg);
    float inv = 1.0f / (l * e0 + l1 * e1);
    float* pq = part + qt * 64 * 33;
    float* mq = merged + qt * 32 * 68;
#pragma unroll
    for (int r = 0; r < 16; ++r) {
      int d = (r & 3) + 8 * (r >> 2) + 4 * hi;
      mq[ql * 68 + d] = (ot0[r] * e0 + pq[d * 33 + ql] * e1) * inv;
      mq[ql * 68 + 32 + d] = (ot1[r] * e0 + pq[(d + 32) * 33 + ql] * e1) * inv;
    }
  }
  __syncthreads();
#pragma unroll
  for (int pss = 0; pss < 2; ++pss) {
    int id = pss * 512 + t;
    int qt2 = id >> 8, row = (id >> 3) & 31, c8 = id & 7;
    const float* mq = merged + qt2 * 32 * 68 + row * 68 + c8 * 8;
    float4 f0 = *(const float4*)mq;
    float4 f1 = *(const float4*)(mq + 4);
    union { ushort us[8]; uint4 u4; } o;
    o.us[0] = f2b(f0.x); o.us[1] = f2b(f0.y); o.us[2] = f2b(f0.z); o.us[3] = f2b(f0.w);
    o.us[4] = f2b(f1.x); o.us[5] = f2b(f1.y); o.us[6] = f2b(f1.z); o.us[7] = f2b(f1.w);
    *(uint4*)(O + (size_t)(q0 + qt2 * 32 + row) * 1024 + h * 64 + c8 * 8) = o.u4;
  }
}

extern "C" void kernel_launch(void* const* d_in, const int* in_sizes, int n_in,
                              void* d_out, int out_size, void* d_ws, size_t ws_size,
                              hipStream_t stream) {
  (void)n_in; (void)out_size; (void)ws_size;
  const float* x    = (const float*)d_in[0];
  const float* Wqkv = (const float*)d_in[1];
  const float* bqkv = (const float*)d_in[2];
  const float* Wout = (const float*)d_in[3];
  const float* bout = (const float*)d_in[4];
  const float* rel  = (const float*)d_in[5];
  float* out = (float*)d_out;
  const int L = in_sizes[0] / 1024;  // 2048

  char* ws = (char*)d_ws;
  const size_t MB = 1024 * 1024;
  ushort* xb  = (ushort*)(ws);             // L*1024 bf16       (4 MB)
  ushort* w1t = (ushort*)(ws + 4 * MB);    // [3072][1024] bf16 (6 MB)
  ushort* w2t = (ushort*)(ws + 10 * MB);   // [1024][1024] bf16 (2 MB)
  ushort* Qsb = (ushort*)(ws + 36 * MB);   // [16][L][64] bf16  (4 MB)
  ushort* Kpb = (ushort*)(ws + 40 * MB);   // [16][L][64] bf16  (4 MB)
  ushort* Vtb = (ushort*)(ws + 44 * MB);   // [16][64][L] bf16  (4 MB)
  ushort* Ob  = (ushort*)(ws + 48 * MB);   // [L][1024] bf16    (4 MB)

  prep<<<dim3((L * 1024) / 1024 + 768 + 256), 256, 0, stream>>>(x, xb, Wqkv, w1t, Wout, w2t, L);
  gemm_qkv<<<dim3(3072 / 128, L / 128), 256, 0, stream>>>(xb, w1t, bqkv, rel, Qsb, Kpb, Vtb, L);
  attn8<<<dim3((L / 128) * 16), 512, 0, stream>>>(Qsb, Kpb, Vtb, Ob, L);
  gemm_dbuf<128, 64, true><<<dim3(1024 / 64, L / 128), 256, 0, stream>>>(Ob, w2t, out, bout, L, 1024, 1024);
}

// Round 15
// 78.020 us; speedup vs baseline: 1.6703x; 1.0512x over previous
//
#include <hip/hip_runtime.h>
#include <hip/hip_bf16.h>
#include <stdint.h>

typedef __attribute__((ext_vector_type(8))) __bf16 bf16x8;
typedef __attribute__((ext_vector_type(4))) float f32x4;
typedef __attribute__((ext_vector_type(16))) float f32x16;
typedef __attribute__((ext_vector_type(2))) uint32_t u32x2;

#define MFMA16(a, b, c) __builtin_amdgcn_mfma_f32_16x16x32_bf16(a, b, c, 0, 0, 0)
#define MFMA32(a, b, c) __builtin_amdgcn_mfma_f32_32x32x16_bf16(a, b, c, 0, 0, 0)

typedef const __attribute__((address_space(1))) uint32_t* gas_ptr;
typedef __attribute__((address_space(3))) uint32_t* lds_ptr;

static __device__ __forceinline__ ushort f2b(float f) {
  union { float f; uint32_t u; } x; x.f = f;
  uint32_t u = x.u + 0x7fffu + ((x.u >> 16) & 1u);
  return (ushort)(u >> 16);
}

static __device__ __forceinline__ void g2lds16(const void* g, void* l) {
  __builtin_amdgcn_global_load_lds((gas_ptr)(uintptr_t)g, (lds_ptr)(uintptr_t)l, 16, 0, 0);
}

// counted vmcnt (T4): leave prefetch in flight across the barrier
template <int N> static __device__ __forceinline__ void waitvm() {
  if constexpr (N == 0) asm volatile("s_waitcnt vmcnt(0)" ::: "memory");
  else if constexpr (N == 2) asm volatile("s_waitcnt vmcnt(2)" ::: "memory");
  else if constexpr (N == 3) asm volatile("s_waitcnt vmcnt(3)" ::: "memory");
  else if constexpr (N == 4) asm volatile("s_waitcnt vmcnt(4)" ::: "memory");
  else if constexpr (N == 6) asm volatile("s_waitcnt vmcnt(6)" ::: "memory");
  else if constexpr (N == 8) asm volatile("s_waitcnt vmcnt(8)" ::: "memory");
}

static __device__ __forceinline__ u32x2 plswap(uint32_t a, uint32_t b) {
  return __builtin_amdgcn_permlane32_swap(a, b, false, false);
}
static __device__ __forceinline__ float xhalf_max(float x) {
  u32x2 r = plswap(__float_as_uint(x), __float_as_uint(x));
  return fmaxf(__uint_as_float(r.x), __uint_as_float(r.y));
}
static __device__ __forceinline__ float xhalf_sum(float x) {
  u32x2 r = plswap(__float_as_uint(x), __float_as_uint(x));
  return __uint_as_float(r.x) + __uint_as_float(r.y);
}

// ---------------- prep: cvt x -> bf16, transpose Wqkv & Wout -> bf16 [N][K] ----------------
__global__ __launch_bounds__(256) void prep(const float* __restrict__ x, ushort* __restrict__ xb,
                                            const float* __restrict__ Wqkv, ushort* __restrict__ w1t,
                                            const float* __restrict__ Wout, ushort* __restrict__ w2t,
                                            int L) {
  const int b = blockIdx.x, t = threadIdx.x;
  const int ncvt = (L * 1024) / (256 * 4);  // 2048
  if (b < ncvt) {
    int i = (b * 256 + t) * 4;
    float4 v = *(const float4*)(x + i);
    ushort4 o;
    o.x = f2b(v.x); o.y = f2b(v.y); o.z = f2b(v.z); o.w = f2b(v.w);
    *(ushort4*)(xb + i) = o;
    return;
  }
  __shared__ ushort tile[64][65];
  const float* in; ushort* out; int N; int b2;
  const int K = 1024;
  if (b < ncvt + 768) { b2 = b - ncvt; N = 3072; in = Wqkv; out = w1t; }
  else                { b2 = b - ncvt - 768; N = 1024; in = Wout; out = w2t; }
  int nx = b2 % (N >> 6), ky = b2 / (N >> 6);
  int n0 = nx * 64, k0 = ky * 64;
#pragma unroll
  for (int i = 0; i < 16; ++i) {
    int idx = i * 256 + t;
    int r = idx >> 6, c = idx & 63;
    tile[r][c] = f2b(in[(size_t)(k0 + r) * N + n0 + c]);
  }
  __syncthreads();
#pragma unroll
  for (int i = 0; i < 16; ++i) {
    int idx = i * 256 + t;
    int r = idx >> 6, c = idx & 63;  // r = n index, c = k index
    out[(size_t)(n0 + r) * K + k0 + c] = tile[c][r];
  }
}

// ---------------- 8-wave dbuf bf16 GEMM (2x4 wave grid): C = A*Bt^T (+bias), fp32 C ----------------
// 512 thr = 8 waves: wr = wid>>2 (2 M-rows), wc = wid&3 (4 N-cols). Same tiles/LDS/swizzle
// as the proven 4-wave version; per-wave output halves -> 2x waves/SIMD at same grid,
// hiding the per-K-step barrier bracket. NO min-waves launch_bounds arg (r3/r12 lesson).
template <int BM, int BN, bool BIAS>
__global__ __launch_bounds__(512) void gemm8(const ushort* __restrict__ A,
                                             const ushort* __restrict__ Bt,
                                             float* __restrict__ C,
                                             const float* __restrict__ bias,
                                             int M, int N, int K) {
  constexpr int WM = BM / 2, WN = BN / 4, MF = WM / 16, NF = WN / 16;
  constexpr int AI = (BM * 64) / (512 * 8);   // 16B loads per thread for A tile
  constexpr int BI = (BN * 64) / (512 * 8);
  __shared__ ushort lA[2][BM * 64];
  __shared__ ushort lB[2][BN * 64];
  const int t = threadIdx.x, lane = t & 63;
  const int bm = blockIdx.y * BM, bn = blockIdx.x * BN;
  const int wid = t >> 6, wr = wid >> 2, wc = wid & 3;

  f32x4 acc[MF][NF] = {};

  auto STAGE = [&](int bb, int k0) {
#pragma unroll
    for (int i = 0; i < AI; ++i) {
      int ci = i * 512 + t;
      int r = ci >> 3, cs = ci & 7;
      int cg = (cs ^ (r & 7)) * 8;
      g2lds16(A + (size_t)(bm + r) * K + k0 + cg, (ushort*)lA[bb] + ci * 8);
    }
#pragma unroll
    for (int i = 0; i < BI; ++i) {
      int ci = i * 512 + t;
      int r = ci >> 3, cs = ci & 7;
      int cg = (cs ^ (r & 7)) * 8;
      g2lds16(Bt + (size_t)(bn + r) * K + k0 + cg, (ushort*)lB[bb] + ci * 8);
    }
  };

  STAGE(0, 0);
  const int NS = K >> 6;
  int buf = 0;
  for (int s = 0; s < NS; ++s) {
    if (s + 1 < NS) { STAGE(buf ^ 1, (s + 1) << 6); waitvm<AI + BI>(); }
    else            { waitvm<0>(); }
    __builtin_amdgcn_s_barrier();
    __builtin_amdgcn_sched_barrier(0);
#pragma unroll
    for (int kk = 0; kk < 2; ++kk) {
      bf16x8 af[MF], bfr[NF];
#pragma unroll
      for (int m = 0; m < MF; ++m) {
        int row = wr * WM + m * 16 + (lane & 15);
        int cb = kk * 64 + ((lane >> 4) << 4);
        int sw = cb ^ ((row & 7) << 4);
        af[m] = *(const bf16x8*)((const char*)lA[buf] + row * 128 + sw);
      }
#pragma unroll
      for (int n = 0; n < NF; ++n) {
        int row = wc * WN + n * 16 + (lane & 15);
        int cb = kk * 64 + ((lane >> 4) << 4);
        int sw = cb ^ ((row & 7) << 4);
        bfr[n] = *(const bf16x8*)((const char*)lB[buf] + row * 128 + sw);
      }
      __builtin_amdgcn_s_setprio(1);
#pragma unroll
      for (int m = 0; m < MF; ++m)
#pragma unroll
        for (int n = 0; n < NF; ++n) acc[m][n] = MFMA16(af[m], bfr[n], acc[m][n]);
      __builtin_amdgcn_s_setprio(0);
    }
    __builtin_amdgcn_s_barrier();      // readers done before next STAGE overwrites
    __builtin_amdgcn_sched_barrier(0);
    buf ^= 1;
  }
#pragma unroll
  for (int m = 0; m < MF; ++m) {
#pragma unroll
    for (int n = 0; n < NF; ++n) {
      int col = bn + wc * WN + n * 16 + (lane & 15);
      float b = BIAS ? bias[col] : 0.f;
#pragma unroll
      for (int r = 0; r < 4; ++r) {
        int row = bm + wr * WM + m * 16 + ((lane >> 4) << 2) + r;
        C[(size_t)row * N + col] = acc[m][n][r] + b;
      }
    }
  }
}

// ---------------- fused qkv GEMM, 8-wave (2x4): x@Wqkv+bias -> Qs, Kp(+rel), Vt ----------------
__global__ __launch_bounds__(512) void gemm_qkv(const ushort* __restrict__ A,
                                                const ushort* __restrict__ Bt,
                                                const float* __restrict__ bqkv,
                                                const float* __restrict__ rel,
                                                ushort* __restrict__ Qs,
                                                ushort* __restrict__ Kp,
                                                ushort* __restrict__ Vt, int M) {
  __shared__ ushort lA[2][128 * 64];
  __shared__ ushort lB[2][128 * 64];
  const int K = 1024;
  const int t = threadIdx.x, lane = t & 63;
  const int bm = blockIdx.y * 128, bn = blockIdx.x * 128;
  const int wid = t >> 6, wr = wid >> 2, wc = wid & 3;   // 2 x 4 wave grid

  f32x4 acc[4][2] = {};   // per-wave 64 x 32

  auto STAGE = [&](int bb, int k0) {
#pragma unroll
    for (int i = 0; i < 2; ++i) {
      int ci = i * 512 + t;
      int r = ci >> 3, cs = ci & 7;
      int cg = (cs ^ (r & 7)) * 8;
      g2lds16(A + (size_t)(bm + r) * K + k0 + cg, (ushort*)lA[bb] + ci * 8);
      g2lds16(Bt + (size_t)(bn + r) * K + k0 + cg, (ushort*)lB[bb] + ci * 8);
    }
  };

  STAGE(0, 0);
  int buf = 0;
  for (int s = 0; s < 16; ++s) {
    if (s + 1 < 16) { STAGE(buf ^ 1, (s + 1) << 6); waitvm<4>(); }
    else            { waitvm<0>(); }
    __builtin_amdgcn_s_barrier();
    __builtin_amdgcn_sched_barrier(0);
#pragma unroll
    for (int kk = 0; kk < 2; ++kk) {
      bf16x8 af[4], bfr[2];
#pragma unroll
      for (int m = 0; m < 4; ++m) {
        int row = wr * 64 + m * 16 + (lane & 15);
        int cb = kk * 64 + ((lane >> 4) << 4);
        int sw = cb ^ ((row & 7) << 4);
        af[m] = *(const bf16x8*)((const char*)lA[buf] + row * 128 + sw);
      }
#pragma unroll
      for (int n = 0; n < 2; ++n) {
        int row = wc * 32 + n * 16 + (lane & 15);
        int cb = kk * 64 + ((lane >> 4) << 4);
        int sw = cb ^ ((row & 7) << 4);
        bfr[n] = *(const bf16x8*)((const char*)lB[buf] + row * 128 + sw);
      }
      __builtin_amdgcn_s_setprio(1);
#pragma unroll
      for (int m = 0; m < 4; ++m)
#pragma unroll
        for (int n = 0; n < 2; ++n) acc[m][n] = MFMA16(af[m], bfr[n], acc[m][n]);
      __builtin_amdgcn_s_setprio(0);
    }
    __builtin_amdgcn_s_barrier();
    __builtin_amdgcn_sched_barrier(0);
    buf ^= 1;
  }

  const int sec = bn >> 10;          // 0=Q, 1=K, 2=V
  const int cis_base = bn & 1023;
  if (sec < 2) {
    ushort* dst = (sec == 0) ? Qs : Kp;
    const float scale = (sec == 0) ? 0.18033688f : 1.0f;  // 0.125*log2(e) for Q
#pragma unroll
    for (int m = 0; m < 4; ++m) {
#pragma unroll
      for (int n = 0; n < 2; ++n) {
        int cis = cis_base + wc * 32 + n * 16 + (lane & 15);
        int hh = cis >> 6, dd = cis & 63;
        float b = bqkv[sec * 1024 + cis];
#pragma unroll
        for (int r = 0; r < 4; ++r) {
          int row = bm + wr * 64 + m * 16 + ((lane >> 4) << 2) + r;
          float v = acc[m][n][r] + b;
          if (sec == 1 && row > 0) v += rel[(size_t)(row - 1) * 64 + dd];
          dst[((size_t)hh * M + row) * 64 + dd] = f2b(v * scale);
        }
      }
    }
  } else {
    // V: bf16 into swizzled LDS [c][l], then coalesced transposed store.
    char* tb = (char*)lA;
#pragma unroll
    for (int m = 0; m < 4; ++m) {
#pragma unroll
      for (int n = 0; n < 2; ++n) {
        int cl = wc * 32 + n * 16 + (lane & 15);
        int ll = wr * 64 + m * 16 + ((lane >> 4) << 2);
        float b = bqkv[2048 + cis_base + cl];
        ushort4 w4;
        w4.x = f2b(acc[m][n][0] + b);
        w4.y = f2b(acc[m][n][1] + b);
        w4.z = f2b(acc[m][n][2] + b);
        w4.w = f2b(acc[m][n][3] + b);
        *(ushort4*)(tb + cl * 256 + ((ll * 2) ^ ((cl & 15) << 4))) = w4;
      }
    }
    __syncthreads();
#pragma unroll
    for (int ps = 0; ps < 4; ++ps) {
      int cl = ps * 32 + (t >> 4);
      int chunk = t & 15;
      uint4 rv = *(const uint4*)(tb + cl * 256 + ((chunk * 16) ^ ((cl & 15) << 4)));
      *(uint4*)(Vt + (size_t)(cis_base + cl) * M + bm + chunk * 8) = rv;
    }
  }
}

// ---------------- flash attention v8 (r9 best): 8 waves, 4 qt x 2 streams, T4+T5 ----------------
__global__ __launch_bounds__(512) void attn8(const ushort* __restrict__ Qs,
                                             const ushort* __restrict__ Kp,
                                             const ushort* __restrict__ Vt,
                                             ushort* __restrict__ O, int L) {
  __shared__ char smem[69632];   // 2 buf x 2 stream x (K 8KB + V 8KB) = 64KB; merge aliased
  __shared__ float mls[4][2][32];
  const int bid = blockIdx.x;
  const int h = (bid & 7) * 2 + (bid >> 7);      // XCD (bid%8) serves heads {2c,2c+1}
  const int q0 = ((bid >> 3) & 15) * 128;
  const int t = threadIdx.x, lane = t & 63, w = t >> 6;
  const int qt = w & 3, ks = w >> 2;
  const int ql = lane & 31, hi = lane >> 5;
  const int sw = (ql & 7) << 4;
  const ushort* kh = Kp + (size_t)h * L * 64;
  const ushort* vh = Vt + (size_t)h * 64 * L;
  const int half = L >> 1;
  const int NT = half >> 6;

  bf16x8 qf[4];
  {
    const ushort* qrow = Qs + ((size_t)h * L + q0 + qt * 32 + ql) * 64 + hi * 8;
#pragma unroll
    for (int c = 0; c < 4; ++c) qf[c] = *(const bf16x8*)(qrow + c * 16);
  }

  f32x16 ot0 = {}, ot1 = {};
  float m = -1e30f, l = 0.f;

  auto STAGE = [&](int bb, int tt) {
    char* base = smem + bb * 32768;
#pragma unroll
    for (int s = 0; s < 2; ++s) {
      int kb = s * half + tt * 64;
      char* sb = base + s * 16384;
      {
        int key = t >> 3, pch = t & 7;
        g2lds16(kh + (((size_t)(kb + key)) << 6) + ((pch ^ (key & 7)) << 3), sb + t * 16);
      }
      {
        int d = t >> 3, pch = t & 7;
        g2lds16(vh + (size_t)d * L + kb + ((pch ^ (d & 7)) << 3), sb + 8192 + t * 16);
      }
    }
  };

  STAGE(0, 0);
  int buf = 0;
  for (int tt = 0; tt < NT; ++tt) {
    if (tt + 1 < NT) { STAGE(buf ^ 1, tt + 1); waitvm<4>(); }
    else             { waitvm<0>(); }
    __builtin_amdgcn_s_barrier();
    __builtin_amdgcn_sched_barrier(0);
    const char* kbuf = smem + buf * 32768 + ks * 16384;
    const char* vbuf = kbuf + 8192;
    f32x16 s0 = {}, s1 = {};
    __builtin_amdgcn_s_setprio(1);
#pragma unroll
    for (int c = 0; c < 4; ++c) {
      bf16x8 k0 = *(const bf16x8*)(kbuf + ql * 128 + (((2 * c + hi) << 4) ^ sw));
      bf16x8 k1 = *(const bf16x8*)(kbuf + (32 + ql) * 128 + (((2 * c + hi) << 4) ^ sw));
      s0 = MFMA32(k0, qf[c], s0);
      s1 = MFMA32(k1, qf[c], s1);
    }
    __builtin_amdgcn_s_setprio(0);
    float mx = fmaxf(s0[0], s1[0]);
#pragma unroll
    for (int i = 1; i < 16; ++i) mx = fmaxf(fmaxf(s0[i], s1[i]), mx);
    mx = xhalf_max(mx);
    if (!__all(mx - m <= 8.0f)) {  // defer-max
      float mn = fmaxf(m, mx);
      float sc = __builtin_amdgcn_exp2f(m - mn);
      m = mn;
      l *= sc;
      ot0 = ot0 * sc;
      ot1 = ot1 * sc;
    }
    float rs = 0.f;
#pragma unroll
    for (int tl = 0; tl < 2; ++tl) {
      f32x16 s = tl ? s1 : s0;
      float p[16];
      float r0 = 0.f, r1 = 0.f;
#pragma unroll
      for (int i = 0; i < 16; i += 2) {
        p[i] = __builtin_amdgcn_exp2f(s[i] - m);
        p[i + 1] = __builtin_amdgcn_exp2f(s[i + 1] - m);
        r0 += p[i];
        r1 += p[i + 1];
      }
      rs += r0 + r1;
      uint32_t a[8];
#pragma unroll
      for (int i = 0; i < 8; ++i) {
        uint32_t r;
        asm("v_cvt_pk_bf16_f32 %0, %1, %2" : "=v"(r) : "v"(p[2 * i]), "v"(p[2 * i + 1]));
        a[i] = r;
      }
      u32x2 s02 = plswap(a[0], a[2]);
      u32x2 s13 = plswap(a[1], a[3]);
      u32x2 s46 = plswap(a[4], a[6]);
      u32x2 s57 = plswap(a[5], a[7]);
      union { uint32_t u[4]; bf16x8 v; } b0, b1;
      b0.u[0] = s02.x; b0.u[1] = s13.x; b0.u[2] = s02.y; b0.u[3] = s13.y;
      b1.u[0] = s46.x; b1.u[1] = s57.x; b1.u[2] = s46.y; b1.u[3] = s57.y;
      bf16x8 v00 = *(const bf16x8*)(vbuf + ql * 128 + (((tl * 4 + hi) << 4) ^ sw));
      bf16x8 v01 = *(const bf16x8*)(vbuf + ql * 128 + (((tl * 4 + 2 + hi) << 4) ^ sw));
      bf16x8 v10 = *(const bf16x8*)(vbuf + (32 + ql) * 128 + (((tl * 4 + hi) << 4) ^ sw));
      bf16x8 v11 = *(const bf16x8*)(vbuf + (32 + ql) * 128 + (((tl * 4 + 2 + hi) << 4) ^ sw));
      __builtin_amdgcn_s_setprio(1);
      ot0 = MFMA32(v00, b0.v, ot0);
      ot0 = MFMA32(v01, b1.v, ot0);
      ot1 = MFMA32(v10, b0.v, ot1);
      ot1 = MFMA32(v11, b1.v, ot1);
      __builtin_amdgcn_s_setprio(0);
    }
    l += xhalf_sum(rs);
    __builtin_amdgcn_s_barrier();      // readers done before next STAGE overwrites
    __builtin_amdgcn_sched_barrier(0);
    buf ^= 1;
  }

  // ---- 2-way flash-merge per q-tile (LDS aliased over stage buffers) ----
  float* part = (float*)smem;                        // [4 qt][64 d][33]
  float* merged = (float*)(smem + 4 * 64 * 33 * 4);  // [4 qt][32 q][68]
  if (ks == 1) {
    if (hi == 0) { mls[qt][0][ql] = m; mls[qt][1][ql] = l; }
    float* pq = part + qt * 64 * 33;
#pragma unroll
    for (int r = 0; r < 16; ++r) {
      int d = (r & 3) + 8 * (r >> 2) + 4 * hi;
      pq[d * 33 + ql] = ot0[r];
      pq[(d + 32) * 33 + ql] = ot1[r];
    }
  }
  __syncthreads();
  if (ks == 0) {
    float m1 = mls[qt][0][ql], l1 = mls[qt][1][ql];
    float mg = fmaxf(m, m1);
    float e0 = __builtin_amdgcn_exp2f(m - mg);
    float e1 = __builtin_amdgcn_exp2f(m1 - mg);
    float inv = 1.0f / (l * e0 + l1 * e1);
    float* pq = part + qt * 64 * 33;
    float* mq = merged + qt * 32 * 68;
#pragma unroll
    for (int r = 0; r < 16; ++r) {
      int d = (r & 3) + 8 * (r >> 2) + 4 * hi;
      mq[ql * 68 + d] = (ot0[r] * e0 + pq[d * 33 + ql] * e1) * inv;
      mq[ql * 68 + 32 + d] = (ot1[r] * e0 + pq[(d + 32) * 33 + ql] * e1) * inv;
    }
  }
  __syncthreads();
#pragma unroll
  for (int pss = 0; pss < 2; ++pss) {
    int id = pss * 512 + t;
    int qt2 = id >> 8, row = (id >> 3) & 31, c8 = id & 7;
    const float* mq = merged + qt2 * 32 * 68 + row * 68 + c8 * 8;
    float4 f0 = *(const float4*)mq;
    float4 f1 = *(const float4*)(mq + 4);
    union { ushort us[8]; uint4 u4; } o;
    o.us[0] = f2b(f0.x); o.us[1] = f2b(f0.y); o.us[2] = f2b(f0.z); o.us[3] = f2b(f0.w);
    o.us[4] = f2b(f1.x); o.us[5] = f2b(f1.y); o.us[6] = f2b(f1.z); o.us[7] = f2b(f1.w);
    *(uint4*)(O + (size_t)(q0 + qt2 * 32 + row) * 1024 + h * 64 + c8 * 8) = o.u4;
  }
}

extern "C" void kernel_launch(void* const* d_in, const int* in_sizes, int n_in,
                              void* d_out, int out_size, void* d_ws, size_t ws_size,
                              hipStream_t stream) {
  (void)n_in; (void)out_size; (void)ws_size;
  const float* x    = (const float*)d_in[0];
  const float* Wqkv = (const float*)d_in[1];
  const float* bqkv = (const float*)d_in[2];
  const float* Wout = (const float*)d_in[3];
  const float* bout = (const float*)d_in[4];
  const float* rel  = (const float*)d_in[5];
  float* out = (float*)d_out;
  const int L = in_sizes[0] / 1024;  // 2048

  char* ws = (char*)d_ws;
  const size_t MB = 1024 * 1024;
  ushort* xb  = (ushort*)(ws);             // L*1024 bf16       (4 MB)
  ushort* w1t = (ushort*)(ws + 4 * MB);    // [3072][1024] bf16 (6 MB)
  ushort* w2t = (ushort*)(ws + 10 * MB);   // [1024][1024] bf16 (2 MB)
  ushort* Qsb = (ushort*)(ws + 36 * MB);   // [16][L][64] bf16  (4 MB)
  ushort* Kpb = (ushort*)(ws + 40 * MB);   // [16][L][64] bf16  (4 MB)
  ushort* Vtb = (ushort*)(ws + 44 * MB);   // [16][64][L] bf16  (4 MB)
  ushort* Ob  = (ushort*)(ws + 48 * MB);   // [L][1024] bf16    (4 MB)

  prep<<<dim3((L * 1024) / 1024 + 768 + 256), 256, 0, stream>>>(x, xb, Wqkv, w1t, Wout, w2t, L);
  gemm_qkv<<<dim3(3072 / 128, L / 128), 512, 0, stream>>>(xb, w1t, bqkv, rel, Qsb, Kpb, Vtb, L);
  attn8<<<dim3((L / 128) * 16), 512, 0, stream>>>(Qsb, Kpb, Vtb, Ob, L);
  gemm8<128, 64, true><<<dim3(1024 / 64, L / 128), 512, 0, stream>>>(Ob, w2t, out, bout, L, 1024, 1024);
}